// Round 10
// baseline (297.162 us; speedup 1.0000x reference)
//
#include <hip/hip_runtime.h>
#include <hip/hip_fp16.h>

#define KD 64        // embedding dim
#define NPC 1024     // nodes per coarse bucket (bucket = dst >> 10)
#define TILE 4096    // edges per csplit tile

__device__ __forceinline__ float h2f(unsigned short u) {
    return __half2float(__ushort_as_half(u));
}
__device__ __forceinline__ unsigned short f2h(float f) {
    return __half_as_ushort(__float2half(f));
}

// ---------------- build: coarse histogram ----------------

__global__ void bhist_kernel(const int* __restrict__ dst, int* __restrict__ cntb,
                             int E, int NBC) {
    extern __shared__ int lcnt[];
    for (int i = threadIdx.x; i < NBC; i += blockDim.x) lcnt[i] = 0;
    __syncthreads();
    for (int i = blockIdx.x * blockDim.x + threadIdx.x; i < E; i += gridDim.x * blockDim.x)
        atomicAdd(&lcnt[dst[i] >> 10], 1);
    __syncthreads();
    for (int i = threadIdx.x; i < NBC; i += blockDim.x) {
        int v = lcnt[i];
        if (v) atomicAdd(&cntb[i], v);
    }
}

// single-block exclusive scan of NBC (<=256) counters -> bptr, cursor
__global__ void scan_small_kernel(const int* __restrict__ cnt, int* __restrict__ bptr,
                                  int* __restrict__ cursor, int n, int E) {
    __shared__ int s[256];
    int t = threadIdx.x;
    int v = (t < n) ? cnt[t] : 0;
    s[t] = v;
    __syncthreads();
    for (int off = 1; off < 256; off <<= 1) {
        int add = (t >= off) ? s[t - off] : 0;
        __syncthreads();
        s[t] += add;
        __syncthreads();
    }
    int excl = s[t] - v;
    if (t < n) { bptr[t] = excl; cursor[t] = excl; }
    if (t == 0) bptr[n] = E;
}

// ---------------- build: tile multisplit (pass 1) ----------------

__global__ __launch_bounds__(256)
void csplit_kernel(const int* __restrict__ src, const int* __restrict__ dst,
                   int* __restrict__ cursor, unsigned int* __restrict__ staged,
                   int E, int NBC, int ntiles) {
    __shared__ unsigned int  ord[TILE];      // 16 KB ordered packed entries
    __shared__ unsigned short obkt[TILE];    // 8 KB bucket id per ordered slot
    __shared__ int hist[256];
    __shared__ int lofs[256];
    __shared__ int gbase[256];
    int tid = threadIdx.x;

    for (int tile = blockIdx.x; tile < ntiles; tile += gridDim.x) {
        int e0 = tile * TILE;
        int n = E - e0; if (n > TILE) n = TILE;

        if (tid < NBC) hist[tid] = 0;
        __syncthreads();
        for (int i = tid; i < n; i += 256)
            atomicAdd(&hist[dst[e0 + i] >> 10], 1);
        __syncthreads();
        int v = (tid < NBC) ? hist[tid] : 0;
        lofs[tid] = v;
        __syncthreads();
        for (int off = 1; off < 256; off <<= 1) {
            int add = (tid >= off) ? lofs[tid - off] : 0;
            __syncthreads();
            lofs[tid] += add;
            __syncthreads();
        }
        int excl = lofs[tid] - v;
        lofs[tid] = excl;
        if (tid < NBC) {
            gbase[tid] = atomicAdd(&cursor[tid], v);
            hist[tid] = 0;
        }
        __syncthreads();
        for (int i = tid; i < n; i += 256) {
            int dd = dst[e0 + i];
            int ss = src[e0 + i];
            int b = dd >> 10;
            int p = lofs[b] + atomicAdd(&hist[b], 1);
            ord[p] = (unsigned int)ss | (((unsigned int)dd & 1023u) << 18);
            obkt[p] = (unsigned short)b;
        }
        __syncthreads();
        for (int i = tid; i < n; i += 256) {
            int b = obkt[i];
            staged[gbase[b] + (i - lofs[b])] = ord[i];
        }
        __syncthreads();
    }
}

// ---------------- build: exact per-bucket sort with 4-padding (pass 2) ----------------

// One block per coarse bucket: 1024-bin LDS counting sort; each node's edge
// list is padded to a multiple of 4 with a sentinel (zero-row) index so the
// gather needs no tail masks. Padded space reserved via global atomic (bucket
// regions land in arbitrary order; row_beg/row_len record positions).
__global__ __launch_bounds__(256)
void csort_kernel(const unsigned int* __restrict__ staged, const int* __restrict__ bptr,
                  int* __restrict__ sorted_src, int* __restrict__ row_beg,
                  int* __restrict__ row_len,
                  float* __restrict__ r, float* __restrict__ rinv,
                  int* __restrict__ pad_cursor, int n_nodes, int zrow) {
    __shared__ int cnt[NPC];
    __shared__ int lofs[NPC];    // padded local offsets
    __shared__ int wsum[256];
    __shared__ int sbase;
    int b = blockIdx.x;
    int tid = threadIdx.x;
    int begin = bptr[b], end = bptr[b + 1];

    for (int i = tid; i < NPC; i += 256) cnt[i] = 0;
    __syncthreads();
    for (int i = begin + tid; i < end; i += 256)
        atomicAdd(&cnt[(staged[i] >> 18) & 1023u], 1);
    __syncthreads();
    int base = tid * 4;
    int c0 = cnt[base], c1 = cnt[base + 1], c2 = cnt[base + 2], c3 = cnt[base + 3];
    int p0 = (c0 + 3) & ~3, p1 = (c1 + 3) & ~3, p2 = (c2 + 3) & ~3, p3 = (c3 + 3) & ~3;
    int tsum = p0 + p1 + p2 + p3;
    wsum[tid] = tsum;
    __syncthreads();
    for (int off = 1; off < 256; off <<= 1) {
        int add = (tid >= off) ? wsum[tid - off] : 0;
        __syncthreads();
        wsum[tid] += add;
        __syncthreads();
    }
    int texcl = wsum[tid] - tsum;
    if (tid == 255) sbase = atomicAdd(pad_cursor, wsum[255]);
    lofs[base]     = texcl;
    lofs[base + 1] = texcl + p0;
    lofs[base + 2] = texcl + p0 + p1;
    lofs[base + 3] = texcl + p0 + p1 + p2;
    __syncthreads();
    int pbase = sbase;
    int node0 = b * NPC + base;
    int cc[4] = {c0, c1, c2, c3};
    int pp[4] = {p0, p1, p2, p3};
    for (int j = 0; j < 4; ++j) {
        int node = node0 + j;
        if (node < n_nodes) {
            float d = fmaxf((float)cc[j], 1.0f);
            row_beg[node] = pbase + lofs[base + j];
            row_len[node] = pp[j];
            r[node] = rsqrtf(d);
            rinv[node] = sqrtf(d);
        }
        // sentinel pads (<=3 per node)
        int o = pbase + lofs[base + j];
        for (int k = cc[j]; k < pp[j]; ++k) sorted_src[o + k] = zrow;
    }
    cnt[base] = 0; cnt[base + 1] = 0; cnt[base + 2] = 0; cnt[base + 3] = 0;
    __syncthreads();
    for (int i = begin + tid; i < end; i += 256) {
        unsigned int u = staged[i];
        int ld = (u >> 18) & 1023u;
        int p = pbase + lofs[ld] + atomicAdd(&cnt[ld], 1);
        sorted_src[p] = (int)(u & 0x3FFFFu);
    }
}

// ---------------- embedding kernels ----------------

// xs0 = fp16((Gu+Gut | Gi+Git) * r[node])
__global__ void combine_kernel(const float4* __restrict__ Gu, const float4* __restrict__ Gi,
                               const float4* __restrict__ Gut, const float4* __restrict__ Git,
                               const float* __restrict__ r,
                               ushort4* __restrict__ xs,
                               int nu4, int total4) {
    for (int i = blockIdx.x * blockDim.x + threadIdx.x; i < total4; i += gridDim.x * blockDim.x) {
        float4 a, b;
        if (i < nu4) { a = Gu[i]; b = Gut[i]; }
        else         { a = Gi[i - nu4]; b = Git[i - nu4]; }
        float rr = r[i >> 4];
        ushort4 p;
        p.x = f2h((a.x + b.x) * rr); p.y = f2h((a.y + b.y) * rr);
        p.z = f2h((a.z + b.z) * rr); p.w = f2h((a.w + b.w) * rr);
        xs[i] = p;
    }
}

// one wave per dst node; 4 subgroups x 16 lanes; 4 edges/subgroup/iter with
// 4 independent ushort4 fp16 loads; rows padded to x4 -> NO tail masks.
// last=0: xs_next = fp16(acc*r*r). last=1: fused epilogue writes final out.
__global__ __launch_bounds__(256)
void gather_kernel(const int* __restrict__ row_beg, const int* __restrict__ row_len,
                   const int* __restrict__ sorted_src,
                   const float* __restrict__ r, const ushort4* __restrict__ xs,
                   ushort4* __restrict__ xs_next,
                   const float4* __restrict__ Gu, const float4* __restrict__ Gi,
                   const float4* __restrict__ Gut, const float4* __restrict__ Git,
                   const float* __restrict__ rinv,
                   const ushort4* __restrict__ xs1, const ushort4* __restrict__ xs2,
                   float4* __restrict__ out, int nu, int N, int last) {
    int wid = (blockIdx.x * blockDim.x + threadIdx.x) >> 6;
    int lane = threadIdx.x & 63;
    if (wid >= N) return;
    int beg = row_beg[wid];
    int end = beg + row_len[wid];
    int sub = lane >> 4;
    int li  = lane & 15;

    float ax = 0.f, ay = 0.f, az = 0.f, aw = 0.f;
    for (int bb = beg; bb < end; bb += 64) {
        int nb = end - bb; if (nb > 64) nb = 64;      // multiple of 4
        int es = sorted_src[bb + lane];
        for (int c = 0; c < nb; c += 16) {
            int j0 = c + sub * 4;
            int s0 = __shfl(es, j0 + 0);
            int s1 = __shfl(es, j0 + 1);
            int s2 = __shfl(es, j0 + 2);
            int s3 = __shfl(es, j0 + 3);
            if (j0 < nb) {
                ushort4 u0 = xs[s0 * 16 + li];
                ushort4 u1 = xs[s1 * 16 + li];
                ushort4 u2 = xs[s2 * 16 + li];
                ushort4 u3 = xs[s3 * 16 + li];
                ax += h2f(u0.x) + h2f(u1.x) + h2f(u2.x) + h2f(u3.x);
                ay += h2f(u0.y) + h2f(u1.y) + h2f(u2.y) + h2f(u3.y);
                az += h2f(u0.z) + h2f(u1.z) + h2f(u2.z) + h2f(u3.z);
                aw += h2f(u0.w) + h2f(u1.w) + h2f(u2.w) + h2f(u3.w);
            }
        }
    }
    ax += __shfl_xor(ax, 16); ay += __shfl_xor(ay, 16);
    az += __shfl_xor(az, 16); aw += __shfl_xor(aw, 16);
    ax += __shfl_xor(ax, 32); ay += __shfl_xor(ay, 32);
    az += __shfl_xor(az, 32); aw += __shfl_xor(aw, 32);

    if (lane < 16) {
        float rr = r[wid];
        int idx = wid * 16 + lane;
        if (!last) {
            float s = rr * rr;
            ushort4 p;
            p.x = f2h(ax * s); p.y = f2h(ay * s);
            p.z = f2h(az * s); p.w = f2h(aw * s);
            xs_next[idx] = p;
        } else {
            const float a1 = 0.5f, a2 = 1.0f / 3.0f, a3 = 0.25f;
            float4 a, b;
            if (wid < nu) { a = Gu[idx]; b = Gut[idx]; }
            else          { int j = idx - nu * 16; a = Gi[j]; b = Git[j]; }
            float rv = rinv[wid];
            ushort4 u1 = xs1[idx];
            ushort4 u2 = xs2[idx];
            float4 o;
            o.x = a.x + b.x + rv * (a1 * h2f(u1.x) + a2 * h2f(u2.x)) + a3 * (ax * rr);
            o.y = a.y + b.y + rv * (a1 * h2f(u1.y) + a2 * h2f(u2.y)) + a3 * (ay * rr);
            o.z = a.z + b.z + rv * (a1 * h2f(u1.z) + a2 * h2f(u2.z)) + a3 * (az * rr);
            o.w = a.w + b.w + rv * (a1 * h2f(u1.w) + a2 * h2f(u2.w)) + a3 * (aw * rr);
            out[idx] = o;
        }
    }
}

// ---------------- launch ----------------

extern "C" void kernel_launch(void* const* d_in, const int* in_sizes, int n_in,
                              void* d_out, int out_size, void* d_ws, size_t ws_size,
                              hipStream_t stream) {
    const float* Gu  = (const float*)d_in[0];
    const float* Gi  = (const float*)d_in[1];
    const float* Gut = (const float*)d_in[2];
    const float* Git = (const float*)d_in[3];
    const int*   edge_index = (const int*)d_in[4];

    const int nuK = in_sizes[0];
    const int niK = in_sizes[1];
    const int n_nodes = (nuK + niK) / KD;        // 150000
    const int E = in_sizes[4] / 2;               // 2,000,000
    const int totalK = nuK + niK;
    const int total4 = totalK / 4;
    const int nu4 = nuK / 4;
    const int nu = nuK / KD;                     // 100000
    const int NBC = (n_nodes + NPC - 1) / NPC;   // 147 coarse buckets
    const int ntiles = (E + TILE - 1) / TILE;    // 489
    const int Epad = E + 3 * n_nodes + 64;       // padded edge capacity

    const int* src = edge_index;
    const int* dst = edge_index + E;

    auto align_up = [](size_t v) { return (v + 255) & ~(size_t)255; };
    char* ws = (char*)d_ws;
    size_t off = 0;
    int*          cntb       = (int*)(ws + off);          off += align_up((size_t)NBC * 4);
    int*          bptr       = (int*)(ws + off);          off += align_up((size_t)(NBC + 1) * 4);
    int*          cursor     = (int*)(ws + off);          off += align_up((size_t)NBC * 4);
    int*          pad_cursor = (int*)(ws + off);          off += align_up((size_t)256);
    int*          row_beg    = (int*)(ws + off);          off += align_up((size_t)n_nodes * 4);
    int*          row_len    = (int*)(ws + off);          off += align_up((size_t)n_nodes * 4);
    float*        r          = (float*)(ws + off);        off += align_up((size_t)n_nodes * 4);
    float*        rinv       = (float*)(ws + off);        off += align_up((size_t)n_nodes * 4);
    unsigned int* staged     = (unsigned int*)(ws + off); off += align_up((size_t)E * 4);
    int*          sorted_src = (int*)(ws + off);          off += align_up((size_t)Epad * 4);
    unsigned short* xs0      = (unsigned short*)(ws + off); off += align_up(((size_t)totalK + KD) * 2);
    unsigned short* xs1      = (unsigned short*)(ws + off); off += align_up(((size_t)totalK + KD) * 2);
    unsigned short* xs2      = (unsigned short*)(ws + off); off += align_up(((size_t)totalK + KD) * 2);
    if (off > ws_size) return;

    float* out = (float*)d_out;

    const int BLK = 256;
    const int grid_v = 2048;
    const int grid_g = (n_nodes * KD + BLK - 1) / BLK;  // 1 wave/node

    // zero the sentinel rows (index n_nodes) and counters
    hipMemsetAsync(cntb, 0, (size_t)NBC * 4, stream);
    hipMemsetAsync(pad_cursor, 0, 4, stream);
    hipMemsetAsync(xs0 + (size_t)n_nodes * KD, 0, KD * 2, stream);
    hipMemsetAsync(xs1 + (size_t)n_nodes * KD, 0, KD * 2, stream);
    hipMemsetAsync(xs2 + (size_t)n_nodes * KD, 0, KD * 2, stream);

    // build: coarse hist -> scan -> tile multisplit -> per-bucket padded sort
    bhist_kernel<<<256, BLK, (size_t)NBC * 4, stream>>>(dst, cntb, E, NBC);
    scan_small_kernel<<<1, 256, 0, stream>>>(cntb, bptr, cursor, NBC, E);
    csplit_kernel<<<ntiles, BLK, 0, stream>>>(src, dst, cursor, staged, E, NBC, ntiles);
    csort_kernel<<<NBC, BLK, 0, stream>>>(staged, bptr, sorted_src, row_beg, row_len,
                                          r, rinv, pad_cursor, n_nodes, n_nodes);

    // xs0 = fp16(x0 * r)
    combine_kernel<<<grid_v, BLK, 0, stream>>>((const float4*)Gu, (const float4*)Gi,
                                               (const float4*)Gut, (const float4*)Git,
                                               r, (ushort4*)xs0, nu4, total4);

    // propagation: xs1, xs2, then fused last layer -> out
    gather_kernel<<<grid_g, BLK, 0, stream>>>(row_beg, row_len, sorted_src, r,
                                              (const ushort4*)xs0, (ushort4*)xs1,
                                              nullptr, nullptr, nullptr, nullptr,
                                              nullptr, nullptr, nullptr, nullptr,
                                              nu, n_nodes, 0);
    gather_kernel<<<grid_g, BLK, 0, stream>>>(row_beg, row_len, sorted_src, r,
                                              (const ushort4*)xs1, (ushort4*)xs2,
                                              nullptr, nullptr, nullptr, nullptr,
                                              nullptr, nullptr, nullptr, nullptr,
                                              nu, n_nodes, 0);
    gather_kernel<<<grid_g, BLK, 0, stream>>>(row_beg, row_len, sorted_src, r,
                                              (const ushort4*)xs2, nullptr,
                                              (const float4*)Gu, (const float4*)Gi,
                                              (const float4*)Gut, (const float4*)Git,
                                              rinv, (const ushort4*)xs1,
                                              (const ushort4*)xs2,
                                              (float4*)out, nu, n_nodes, 1);
}

// Round 11
// 283.268 us; speedup vs baseline: 1.0490x; 1.0490x over previous
//
#include <hip/hip_runtime.h>
#include <hip/hip_fp16.h>

#define KD 64        // embedding dim
#define NPC 1024     // nodes per coarse bucket (bucket = dst >> 10)
#define TILE 4096    // edges per csplit tile

__device__ __forceinline__ float h2f(unsigned short u) {
    return __half2float(__ushort_as_half(u));
}
__device__ __forceinline__ unsigned short f2h(float f) {
    return __half_as_ushort(__float2half(f));
}

// ---------------- build: coarse histogram ----------------

__global__ void bhist_kernel(const int* __restrict__ dst, int* __restrict__ cntb,
                             int E, int NBC) {
    extern __shared__ int lcnt[];
    for (int i = threadIdx.x; i < NBC; i += blockDim.x) lcnt[i] = 0;
    __syncthreads();
    for (int i = blockIdx.x * blockDim.x + threadIdx.x; i < E; i += gridDim.x * blockDim.x)
        atomicAdd(&lcnt[dst[i] >> 10], 1);
    __syncthreads();
    for (int i = threadIdx.x; i < NBC; i += blockDim.x) {
        int v = lcnt[i];
        if (v) atomicAdd(&cntb[i], v);
    }
}

// single-block exclusive scan of NBC (<=256) counters -> bptr, cursor
__global__ void scan_small_kernel(const int* __restrict__ cnt, int* __restrict__ bptr,
                                  int* __restrict__ cursor, int n, int E) {
    __shared__ int s[256];
    int t = threadIdx.x;
    int v = (t < n) ? cnt[t] : 0;
    s[t] = v;
    __syncthreads();
    for (int off = 1; off < 256; off <<= 1) {
        int add = (t >= off) ? s[t - off] : 0;
        __syncthreads();
        s[t] += add;
        __syncthreads();
    }
    int excl = s[t] - v;
    if (t < n) { bptr[t] = excl; cursor[t] = excl; }
    if (t == 0) bptr[n] = E;
}

// ---------------- build: tile multisplit (pass 1) ----------------

__global__ __launch_bounds__(256)
void csplit_kernel(const int* __restrict__ src, const int* __restrict__ dst,
                   int* __restrict__ cursor, unsigned int* __restrict__ staged,
                   int E, int NBC, int ntiles) {
    __shared__ unsigned int  ord[TILE];      // 16 KB ordered packed entries
    __shared__ unsigned short obkt[TILE];    // 8 KB bucket id per ordered slot
    __shared__ int hist[256];
    __shared__ int lofs[256];
    __shared__ int gbase[256];
    int tid = threadIdx.x;

    for (int tile = blockIdx.x; tile < ntiles; tile += gridDim.x) {
        int e0 = tile * TILE;
        int n = E - e0; if (n > TILE) n = TILE;

        if (tid < NBC) hist[tid] = 0;
        __syncthreads();
        for (int i = tid; i < n; i += 256)
            atomicAdd(&hist[dst[e0 + i] >> 10], 1);
        __syncthreads();
        int v = (tid < NBC) ? hist[tid] : 0;
        lofs[tid] = v;
        __syncthreads();
        for (int off = 1; off < 256; off <<= 1) {
            int add = (tid >= off) ? lofs[tid - off] : 0;
            __syncthreads();
            lofs[tid] += add;
            __syncthreads();
        }
        int excl = lofs[tid] - v;
        lofs[tid] = excl;
        if (tid < NBC) {
            gbase[tid] = atomicAdd(&cursor[tid], v);
            hist[tid] = 0;
        }
        __syncthreads();
        for (int i = tid; i < n; i += 256) {
            int dd = dst[e0 + i];
            int ss = src[e0 + i];
            int b = dd >> 10;
            int p = lofs[b] + atomicAdd(&hist[b], 1);
            ord[p] = (unsigned int)ss | (((unsigned int)dd & 1023u) << 18);
            obkt[p] = (unsigned short)b;
        }
        __syncthreads();
        for (int i = tid; i < n; i += 256) {
            int b = obkt[i];
            staged[gbase[b] + (i - lofs[b])] = ord[i];
        }
        __syncthreads();
    }
}

// ---------------- build: exact per-bucket sort (pass 2) ----------------

__global__ __launch_bounds__(256)
void csort_kernel(const unsigned int* __restrict__ staged, const int* __restrict__ bptr,
                  int* __restrict__ sorted_src, int* __restrict__ row_ptr,
                  float* __restrict__ r, float* __restrict__ rinv,
                  int n_nodes, int E) {
    __shared__ int cnt[NPC];
    __shared__ int lofs[NPC];
    __shared__ int wsum[256];
    int b = blockIdx.x;
    int tid = threadIdx.x;
    int begin = bptr[b], end = bptr[b + 1];

    for (int i = tid; i < NPC; i += 256) cnt[i] = 0;
    __syncthreads();
    for (int i = begin + tid; i < end; i += 256)
        atomicAdd(&cnt[(staged[i] >> 18) & 1023u], 1);
    __syncthreads();
    int base = tid * 4;
    int c0 = cnt[base], c1 = cnt[base + 1], c2 = cnt[base + 2], c3 = cnt[base + 3];
    int tsum = c0 + c1 + c2 + c3;
    wsum[tid] = tsum;
    __syncthreads();
    for (int off = 1; off < 256; off <<= 1) {
        int add = (tid >= off) ? wsum[tid - off] : 0;
        __syncthreads();
        wsum[tid] += add;
        __syncthreads();
    }
    int texcl = wsum[tid] - tsum;
    lofs[base]     = texcl;
    lofs[base + 1] = texcl + c0;
    lofs[base + 2] = texcl + c0 + c1;
    lofs[base + 3] = texcl + c0 + c1 + c2;
    int node0 = b * NPC + base;
    int cc[4] = {c0, c1, c2, c3};
    for (int j = 0; j < 4; ++j) {
        int node = node0 + j;
        if (node < n_nodes) {
            float d = fmaxf((float)cc[j], 1.0f);
            row_ptr[node] = begin + lofs[base + j];
            r[node] = rsqrtf(d);
            rinv[node] = sqrtf(d);
        }
    }
    cnt[base] = 0; cnt[base + 1] = 0; cnt[base + 2] = 0; cnt[base + 3] = 0;
    if (b == 0 && tid == 0) row_ptr[n_nodes] = E;
    __syncthreads();
    for (int i = begin + tid; i < end; i += 256) {
        unsigned int u = staged[i];
        int ld = (u >> 18) & 1023u;
        int p = begin + lofs[ld] + atomicAdd(&cnt[ld], 1);
        sorted_src[p] = (int)(u & 0x3FFFFu);
    }
}

// ---------------- embedding kernels ----------------

// xs0 = fp16((Gu+Gut | Gi+Git) * r[node])
__global__ void combine_kernel(const float4* __restrict__ Gu, const float4* __restrict__ Gi,
                               const float4* __restrict__ Gut, const float4* __restrict__ Git,
                               const float* __restrict__ r,
                               ushort4* __restrict__ xs,
                               int nu4, int total4) {
    for (int i = blockIdx.x * blockDim.x + threadIdx.x; i < total4; i += gridDim.x * blockDim.x) {
        float4 a, b;
        if (i < nu4) { a = Gu[i]; b = Gut[i]; }
        else         { a = Gi[i - nu4]; b = Git[i - nu4]; }
        float rr = r[i >> 4];
        ushort4 p;
        p.x = f2h((a.x + b.x) * rr); p.y = f2h((a.y + b.y) * rr);
        p.z = f2h((a.z + b.z) * rr); p.w = f2h((a.w + b.w) * rr);
        xs[i] = p;
    }
}

// one wave per dst node; 4 subgroups x 16 lanes; 4 edges/subgroup/iter with
// 4 independent 8B fp16 loads. Invalid tail slots select a zeroed sentinel
// row (index zrow) -> no float masks. Packed __hadd2 tree (depth 2, fp16)
// combines the 4 edges, then 2 cvt-pairs + 4 f32 adds into the accumulator.
// xs_next = fp16(acc * r * r).
__global__ __launch_bounds__(256)
void gather_kernel(const int* __restrict__ row_ptr, const int* __restrict__ sorted_src,
                   const float* __restrict__ r, const uint2* __restrict__ xs,
                   ushort4* __restrict__ xs_next, int N, int zrow) {
    int wid = (blockIdx.x * blockDim.x + threadIdx.x) >> 6;
    int lane = threadIdx.x & 63;
    if (wid >= N) return;
    int start = row_ptr[wid];
    int end   = row_ptr[wid + 1];
    int sub = lane >> 4;      // edge subgroup 0..3
    int li  = lane & 15;      // 8B slot within the 64-dim fp16 row

    float ax = 0.f, ay = 0.f, az = 0.f, aw = 0.f;
    for (int base = start; base < end; base += 64) {
        int nb = end - base; if (nb > 64) nb = 64;
        int eaddr = base + lane;
        int laste = end - 1;
        if (eaddr > laste) eaddr = laste;
        int es = sorted_src[eaddr];              // 64 edge ids (clamped tail)
        for (int c = 0; c < nb; c += 16) {
            int j0 = c + sub * 4;
            int s0 = __shfl(es, j0 + 0);
            int s1 = __shfl(es, j0 + 1);
            int s2 = __shfl(es, j0 + 2);
            int s3 = __shfl(es, j0 + 3);
            s1 = (j0 + 1 < nb) ? s1 : zrow;
            s2 = (j0 + 2 < nb) ? s2 : zrow;
            s3 = (j0 + 3 < nb) ? s3 : zrow;
            if (j0 < nb) {
                uint2 w0 = xs[s0 * 16 + li];
                uint2 w1 = xs[s1 * 16 + li];
                uint2 w2 = xs[s2 * 16 + li];
                uint2 w3 = xs[s3 * 16 + li];
                __half2 a0 = __builtin_bit_cast(__half2, w0.x);
                __half2 a1 = __builtin_bit_cast(__half2, w1.x);
                __half2 a2 = __builtin_bit_cast(__half2, w2.x);
                __half2 a3 = __builtin_bit_cast(__half2, w3.x);
                __half2 b0 = __builtin_bit_cast(__half2, w0.y);
                __half2 b1 = __builtin_bit_cast(__half2, w1.y);
                __half2 b2 = __builtin_bit_cast(__half2, w2.y);
                __half2 b3 = __builtin_bit_cast(__half2, w3.y);
                __half2 sa = __hadd2(__hadd2(a0, a1), __hadd2(a2, a3));
                __half2 sb = __hadd2(__hadd2(b0, b1), __hadd2(b2, b3));
                float2 fa = __half22float2(sa);
                float2 fb = __half22float2(sb);
                ax += fa.x; ay += fa.y; az += fb.x; aw += fb.y;
            }
        }
    }
    ax += __shfl_xor(ax, 16); ay += __shfl_xor(ay, 16);
    az += __shfl_xor(az, 16); aw += __shfl_xor(aw, 16);
    ax += __shfl_xor(ax, 32); ay += __shfl_xor(ay, 32);
    az += __shfl_xor(az, 32); aw += __shfl_xor(aw, 32);

    if (lane < 16) {
        float rr = r[wid];
        float s = rr * rr;
        ushort4 p;
        p.x = f2h(ax * s); p.y = f2h(ay * s);
        p.z = f2h(az * s); p.w = f2h(aw * s);
        xs_next[wid * 16 + lane] = p;
    }
}

// out = (Gu+Gut | Gi+Git) + rinv[node] * (a1*xs1 + a2*xs2 + a3*xs3)
__global__ void epilogue_kernel(const float4* __restrict__ Gu, const float4* __restrict__ Gi,
                                const float4* __restrict__ Gut, const float4* __restrict__ Git,
                                const float* __restrict__ rinv,
                                const ushort4* __restrict__ xs1,
                                const ushort4* __restrict__ xs2,
                                const ushort4* __restrict__ xs3,
                                float4* __restrict__ out,
                                int nu4, int total4) {
    const float a1 = 0.5f, a2 = 1.0f / 3.0f, a3 = 0.25f;
    for (int i = blockIdx.x * blockDim.x + threadIdx.x; i < total4; i += gridDim.x * blockDim.x) {
        float4 a, b;
        if (i < nu4) { a = Gu[i]; b = Gut[i]; }
        else         { a = Gi[i - nu4]; b = Git[i - nu4]; }
        float rv = rinv[i >> 4];
        ushort4 u1 = xs1[i];
        ushort4 u2 = xs2[i];
        ushort4 u3 = xs3[i];
        float4 o;
        o.x = a.x + b.x + rv * (a1 * h2f(u1.x) + a2 * h2f(u2.x) + a3 * h2f(u3.x));
        o.y = a.y + b.y + rv * (a1 * h2f(u1.y) + a2 * h2f(u2.y) + a3 * h2f(u3.y));
        o.z = a.z + b.z + rv * (a1 * h2f(u1.z) + a2 * h2f(u2.z) + a3 * h2f(u3.z));
        o.w = a.w + b.w + rv * (a1 * h2f(u1.w) + a2 * h2f(u2.w) + a3 * h2f(u3.w));
        out[i] = o;
    }
}

// ---------------- launch ----------------

extern "C" void kernel_launch(void* const* d_in, const int* in_sizes, int n_in,
                              void* d_out, int out_size, void* d_ws, size_t ws_size,
                              hipStream_t stream) {
    const float* Gu  = (const float*)d_in[0];
    const float* Gi  = (const float*)d_in[1];
    const float* Gut = (const float*)d_in[2];
    const float* Git = (const float*)d_in[3];
    const int*   edge_index = (const int*)d_in[4];

    const int nuK = in_sizes[0];
    const int niK = in_sizes[1];
    const int n_nodes = (nuK + niK) / KD;        // 150000
    const int E = in_sizes[4] / 2;               // 2,000,000
    const int totalK = nuK + niK;
    const int total4 = totalK / 4;
    const int nu4 = nuK / 4;
    const int NBC = (n_nodes + NPC - 1) / NPC;   // 147 coarse buckets
    const int ntiles = (E + TILE - 1) / TILE;    // 489

    const int* src = edge_index;
    const int* dst = edge_index + E;

    auto align_up = [](size_t v) { return (v + 255) & ~(size_t)255; };
    char* ws = (char*)d_ws;
    size_t off = 0;
    int*          cntb       = (int*)(ws + off);          off += align_up((size_t)NBC * 4);
    int*          bptr       = (int*)(ws + off);          off += align_up((size_t)(NBC + 1) * 4);
    int*          cursor     = (int*)(ws + off);          off += align_up((size_t)NBC * 4);
    int*          row_ptr    = (int*)(ws + off);          off += align_up((size_t)(n_nodes + 1) * 4);
    float*        r          = (float*)(ws + off);        off += align_up((size_t)n_nodes * 4);
    float*        rinv       = (float*)(ws + off);        off += align_up((size_t)n_nodes * 4);
    unsigned int* staged     = (unsigned int*)(ws + off); off += align_up((size_t)E * 4);
    int*          sorted_src = (int*)(ws + off);          off += align_up((size_t)E * 4);
    unsigned short* xs0      = (unsigned short*)(ws + off); off += align_up(((size_t)totalK + KD) * 2);
    unsigned short* xs1      = (unsigned short*)(ws + off); off += align_up(((size_t)totalK + KD) * 2);
    unsigned short* xs2      = (unsigned short*)(ws + off); off += align_up(((size_t)totalK + KD) * 2);
    unsigned short* xs3      = (unsigned short*)(ws + off); off += align_up(((size_t)totalK + KD) * 2);
    if (off > ws_size) return;

    float* out = (float*)d_out;

    const int BLK = 256;
    const int grid_v = 2048;
    const int grid_g = (n_nodes * KD + BLK - 1) / BLK;  // 1 wave/node
    const int zrow = n_nodes;                            // zeroed sentinel row

    // zero sentinel rows + counters
    hipMemsetAsync(cntb, 0, (size_t)NBC * 4, stream);
    hipMemsetAsync(xs0 + (size_t)n_nodes * KD, 0, KD * 2, stream);
    hipMemsetAsync(xs1 + (size_t)n_nodes * KD, 0, KD * 2, stream);
    hipMemsetAsync(xs2 + (size_t)n_nodes * KD, 0, KD * 2, stream);

    // build: coarse hist -> scan -> tile multisplit -> per-bucket exact sort
    bhist_kernel<<<256, BLK, (size_t)NBC * 4, stream>>>(dst, cntb, E, NBC);
    scan_small_kernel<<<1, 256, 0, stream>>>(cntb, bptr, cursor, NBC, E);
    csplit_kernel<<<ntiles, BLK, 0, stream>>>(src, dst, cursor, staged, E, NBC, ntiles);
    csort_kernel<<<NBC, BLK, 0, stream>>>(staged, bptr, sorted_src, row_ptr, r, rinv,
                                          n_nodes, E);

    // xs0 = fp16(x0 * r)
    combine_kernel<<<grid_v, BLK, 0, stream>>>((const float4*)Gu, (const float4*)Gi,
                                               (const float4*)Gut, (const float4*)Git,
                                               r, (ushort4*)xs0, nu4, total4);

    // propagation (each layer writes xs_k = fp16(y_k * r))
    gather_kernel<<<grid_g, BLK, 0, stream>>>(row_ptr, sorted_src, r,
                                              (const uint2*)xs0, (ushort4*)xs1, n_nodes, zrow);
    gather_kernel<<<grid_g, BLK, 0, stream>>>(row_ptr, sorted_src, r,
                                              (const uint2*)xs1, (ushort4*)xs2, n_nodes, zrow);
    gather_kernel<<<grid_g, BLK, 0, stream>>>(row_ptr, sorted_src, r,
                                              (const uint2*)xs2, (ushort4*)xs3, n_nodes, zrow);

    // out = x0 + rinv * (a1*xs1 + a2*xs2 + a3*xs3)
    epilogue_kernel<<<grid_v, BLK, 0, stream>>>((const float4*)Gu, (const float4*)Gi,
                                                (const float4*)Gut, (const float4*)Git,
                                                rinv, (const ushort4*)xs1,
                                                (const ushort4*)xs2, (const ushort4*)xs3,
                                                (float4*)out, nu4, total4);
}

// Round 12
// 266.824 us; speedup vs baseline: 1.1137x; 1.0616x over previous
//
#include <hip/hip_runtime.h>
#include <hip/hip_fp16.h>

#define KD 64        // embedding dim
#define NPC 1024     // nodes per coarse bucket (bucket = dst >> 10)
#define TILE 4096    // edges per csplit tile

__device__ __forceinline__ float h2f(unsigned short u) {
    return __half2float(__ushort_as_half(u));
}
__device__ __forceinline__ unsigned short f2h(float f) {
    return __half_as_ushort(__float2half(f));
}

// ---------------- build: coarse histogram ----------------

__global__ void bhist_kernel(const int* __restrict__ dst, int* __restrict__ cntb,
                             int E, int NBC) {
    extern __shared__ int lcnt[];
    for (int i = threadIdx.x; i < NBC; i += blockDim.x) lcnt[i] = 0;
    __syncthreads();
    for (int i = blockIdx.x * blockDim.x + threadIdx.x; i < E; i += gridDim.x * blockDim.x)
        atomicAdd(&lcnt[dst[i] >> 10], 1);
    __syncthreads();
    for (int i = threadIdx.x; i < NBC; i += blockDim.x) {
        int v = lcnt[i];
        if (v) atomicAdd(&cntb[i], v);
    }
}

// single-block exclusive scan of NBC (<=256) counters -> bptr, cursor
__global__ void scan_small_kernel(const int* __restrict__ cnt, int* __restrict__ bptr,
                                  int* __restrict__ cursor, int n, int E) {
    __shared__ int s[256];
    int t = threadIdx.x;
    int v = (t < n) ? cnt[t] : 0;
    s[t] = v;
    __syncthreads();
    for (int off = 1; off < 256; off <<= 1) {
        int add = (t >= off) ? s[t - off] : 0;
        __syncthreads();
        s[t] += add;
        __syncthreads();
    }
    int excl = s[t] - v;
    if (t < n) { bptr[t] = excl; cursor[t] = excl; }
    if (t == 0) bptr[n] = E;
}

// ---------------- build: tile multisplit (pass 1) ----------------

__global__ __launch_bounds__(256)
void csplit_kernel(const int* __restrict__ src, const int* __restrict__ dst,
                   int* __restrict__ cursor, unsigned int* __restrict__ staged,
                   int E, int NBC, int ntiles) {
    __shared__ unsigned int  ord[TILE];      // 16 KB ordered packed entries
    __shared__ unsigned short obkt[TILE];    // 8 KB bucket id per ordered slot
    __shared__ int hist[256];
    __shared__ int lofs[256];
    __shared__ int gbase[256];
    int tid = threadIdx.x;

    for (int tile = blockIdx.x; tile < ntiles; tile += gridDim.x) {
        int e0 = tile * TILE;
        int n = E - e0; if (n > TILE) n = TILE;

        if (tid < NBC) hist[tid] = 0;
        __syncthreads();
        for (int i = tid; i < n; i += 256)
            atomicAdd(&hist[dst[e0 + i] >> 10], 1);
        __syncthreads();
        int v = (tid < NBC) ? hist[tid] : 0;
        lofs[tid] = v;
        __syncthreads();
        for (int off = 1; off < 256; off <<= 1) {
            int add = (tid >= off) ? lofs[tid - off] : 0;
            __syncthreads();
            lofs[tid] += add;
            __syncthreads();
        }
        int excl = lofs[tid] - v;
        lofs[tid] = excl;
        if (tid < NBC) {
            gbase[tid] = atomicAdd(&cursor[tid], v);
            hist[tid] = 0;
        }
        __syncthreads();
        for (int i = tid; i < n; i += 256) {
            int dd = dst[e0 + i];
            int ss = src[e0 + i];
            int b = dd >> 10;
            int p = lofs[b] + atomicAdd(&hist[b], 1);
            ord[p] = (unsigned int)ss | (((unsigned int)dd & 1023u) << 18);
            obkt[p] = (unsigned short)b;
        }
        __syncthreads();
        for (int i = tid; i < n; i += 256) {
            int b = obkt[i];
            staged[gbase[b] + (i - lofs[b])] = ord[i];
        }
        __syncthreads();
    }
}

// ---------------- build: exact per-bucket sort (pass 2) ----------------

__global__ __launch_bounds__(256)
void csort_kernel(const unsigned int* __restrict__ staged, const int* __restrict__ bptr,
                  int* __restrict__ sorted_src, int2* __restrict__ rowinfo,
                  float* __restrict__ r, float* __restrict__ rinv,
                  int n_nodes, int E) {
    __shared__ int cnt[NPC];
    __shared__ int lofs[NPC];
    __shared__ int wsum[256];
    int b = blockIdx.x;
    int tid = threadIdx.x;
    int begin = bptr[b], end = bptr[b + 1];

    for (int i = tid; i < NPC; i += 256) cnt[i] = 0;
    __syncthreads();
    for (int i = begin + tid; i < end; i += 256)
        atomicAdd(&cnt[(staged[i] >> 18) & 1023u], 1);
    __syncthreads();
    int base = tid * 4;
    int c0 = cnt[base], c1 = cnt[base + 1], c2 = cnt[base + 2], c3 = cnt[base + 3];
    int tsum = c0 + c1 + c2 + c3;
    wsum[tid] = tsum;
    __syncthreads();
    for (int off = 1; off < 256; off <<= 1) {
        int add = (tid >= off) ? wsum[tid - off] : 0;
        __syncthreads();
        wsum[tid] += add;
        __syncthreads();
    }
    int texcl = wsum[tid] - tsum;
    lofs[base]     = texcl;
    lofs[base + 1] = texcl + c0;
    lofs[base + 2] = texcl + c0 + c1;
    lofs[base + 3] = texcl + c0 + c1 + c2;
    int node0 = b * NPC + base;
    int cc[4] = {c0, c1, c2, c3};
    for (int j = 0; j < 4; ++j) {
        int node = node0 + j;
        if (node < n_nodes) {
            float d = fmaxf((float)cc[j], 1.0f);
            rowinfo[node] = make_int2(begin + lofs[base + j], cc[j]);
            r[node] = rsqrtf(d);
            rinv[node] = sqrtf(d);
        }
    }
    cnt[base] = 0; cnt[base + 1] = 0; cnt[base + 2] = 0; cnt[base + 3] = 0;
    __syncthreads();
    for (int i = begin + tid; i < end; i += 256) {
        unsigned int u = staged[i];
        int ld = (u >> 18) & 1023u;
        int p = begin + lofs[ld] + atomicAdd(&cnt[ld], 1);
        sorted_src[p] = (int)(u & 0x3FFFFu);
    }
}

// ---------------- embedding kernels ----------------

// xs0 = fp16((Gu+Gut | Gi+Git) * r[node])
__global__ void combine_kernel(const float4* __restrict__ Gu, const float4* __restrict__ Gi,
                               const float4* __restrict__ Gut, const float4* __restrict__ Git,
                               const float* __restrict__ r,
                               ushort4* __restrict__ xs,
                               int nu4, int total4) {
    for (int i = blockIdx.x * blockDim.x + threadIdx.x; i < total4; i += gridDim.x * blockDim.x) {
        float4 a, b;
        if (i < nu4) { a = Gu[i]; b = Gut[i]; }
        else         { a = Gi[i - nu4]; b = Git[i - nu4]; }
        float rr = r[i >> 4];
        ushort4 p;
        p.x = f2h((a.x + b.x) * rr); p.y = f2h((a.y + b.y) * rr);
        p.z = f2h((a.z + b.z) * rr); p.w = f2h((a.w + b.w) * rr);
        xs[i] = p;
    }
}

// one wave per dst node; 4 subgroups x 16 lanes; 4 edges/subgroup/iter with
// 4 independent 8B fp16 loads; invalid tail slots select a zeroed sentinel
// row. rowinfo = single 8B {beg,cnt} load. last=0: xs_next = fp16(acc*r*r);
// last=1: fused epilogue writes final out.
__global__ __launch_bounds__(256)
void gather_kernel(const int2* __restrict__ rowinfo, const int* __restrict__ sorted_src,
                   const float* __restrict__ r, const uint2* __restrict__ xs,
                   ushort4* __restrict__ xs_next,
                   const float4* __restrict__ Gu, const float4* __restrict__ Gi,
                   const float4* __restrict__ Gut, const float4* __restrict__ Git,
                   const float* __restrict__ rinv,
                   const ushort4* __restrict__ xs1, const ushort4* __restrict__ xs2,
                   float4* __restrict__ out, int nu, int N, int zrow, int last) {
    int wid = (blockIdx.x * blockDim.x + threadIdx.x) >> 6;
    int lane = threadIdx.x & 63;
    if (wid >= N) return;
    int2 ri = rowinfo[wid];
    int start = ri.x;
    int end   = ri.x + ri.y;
    int sub = lane >> 4;      // edge subgroup 0..3
    int li  = lane & 15;      // 8B slot within the 64-dim fp16 row

    float ax = 0.f, ay = 0.f, az = 0.f, aw = 0.f;
    for (int base = start; base < end; base += 64) {
        int nb = end - base; if (nb > 64) nb = 64;
        int eaddr = base + lane;
        int laste = end - 1;
        if (eaddr > laste) eaddr = laste;
        int es = sorted_src[eaddr];              // 64 edge ids (clamped tail)
        for (int c = 0; c < nb; c += 16) {
            int j0 = c + sub * 4;
            int s0 = __shfl(es, j0 + 0);
            int s1 = __shfl(es, j0 + 1);
            int s2 = __shfl(es, j0 + 2);
            int s3 = __shfl(es, j0 + 3);
            s1 = (j0 + 1 < nb) ? s1 : zrow;
            s2 = (j0 + 2 < nb) ? s2 : zrow;
            s3 = (j0 + 3 < nb) ? s3 : zrow;
            if (j0 < nb) {
                uint2 w0 = xs[s0 * 16 + li];
                uint2 w1 = xs[s1 * 16 + li];
                uint2 w2 = xs[s2 * 16 + li];
                uint2 w3 = xs[s3 * 16 + li];
                __half2 a0 = __builtin_bit_cast(__half2, w0.x);
                __half2 a1 = __builtin_bit_cast(__half2, w1.x);
                __half2 a2 = __builtin_bit_cast(__half2, w2.x);
                __half2 a3 = __builtin_bit_cast(__half2, w3.x);
                __half2 b0 = __builtin_bit_cast(__half2, w0.y);
                __half2 b1 = __builtin_bit_cast(__half2, w1.y);
                __half2 b2 = __builtin_bit_cast(__half2, w2.y);
                __half2 b3 = __builtin_bit_cast(__half2, w3.y);
                __half2 sa = __hadd2(__hadd2(a0, a1), __hadd2(a2, a3));
                __half2 sb = __hadd2(__hadd2(b0, b1), __hadd2(b2, b3));
                float2 fa = __half22float2(sa);
                float2 fb = __half22float2(sb);
                ax += fa.x; ay += fa.y; az += fb.x; aw += fb.y;
            }
        }
    }
    ax += __shfl_xor(ax, 16); ay += __shfl_xor(ay, 16);
    az += __shfl_xor(az, 16); aw += __shfl_xor(aw, 16);
    ax += __shfl_xor(ax, 32); ay += __shfl_xor(ay, 32);
    az += __shfl_xor(az, 32); aw += __shfl_xor(aw, 32);

    if (lane < 16) {
        float rr = r[wid];
        int idx = wid * 16 + lane;
        if (!last) {
            float s = rr * rr;
            ushort4 p;
            p.x = f2h(ax * s); p.y = f2h(ay * s);
            p.z = f2h(az * s); p.w = f2h(aw * s);
            xs_next[idx] = p;
        } else {
            const float a1 = 0.5f, a2 = 1.0f / 3.0f, a3 = 0.25f;
            float4 a, b;
            if (wid < nu) { a = Gu[idx]; b = Gut[idx]; }
            else          { int j = idx - nu * 16; a = Gi[j]; b = Git[j]; }
            float rv = rinv[wid];
            ushort4 u1 = xs1[idx];
            ushort4 u2 = xs2[idx];
            float4 o;
            o.x = a.x + b.x + rv * (a1 * h2f(u1.x) + a2 * h2f(u2.x)) + a3 * (ax * rr);
            o.y = a.y + b.y + rv * (a1 * h2f(u1.y) + a2 * h2f(u2.y)) + a3 * (ay * rr);
            o.z = a.z + b.z + rv * (a1 * h2f(u1.z) + a2 * h2f(u2.z)) + a3 * (az * rr);
            o.w = a.w + b.w + rv * (a1 * h2f(u1.w) + a2 * h2f(u2.w)) + a3 * (aw * rr);
            out[idx] = o;
        }
    }
}

// ---------------- launch ----------------

extern "C" void kernel_launch(void* const* d_in, const int* in_sizes, int n_in,
                              void* d_out, int out_size, void* d_ws, size_t ws_size,
                              hipStream_t stream) {
    const float* Gu  = (const float*)d_in[0];
    const float* Gi  = (const float*)d_in[1];
    const float* Gut = (const float*)d_in[2];
    const float* Git = (const float*)d_in[3];
    const int*   edge_index = (const int*)d_in[4];

    const int nuK = in_sizes[0];
    const int niK = in_sizes[1];
    const int n_nodes = (nuK + niK) / KD;        // 150000
    const int E = in_sizes[4] / 2;               // 2,000,000
    const int totalK = nuK + niK;
    const int total4 = totalK / 4;
    const int nu4 = nuK / 4;
    const int nu = nuK / KD;                     // 100000
    const int NBC = (n_nodes + NPC - 1) / NPC;   // 147 coarse buckets
    const int ntiles = (E + TILE - 1) / TILE;    // 489

    const int* src = edge_index;
    const int* dst = edge_index + E;

    auto align_up = [](size_t v) { return (v + 255) & ~(size_t)255; };
    char* ws = (char*)d_ws;
    size_t off = 0;
    int*          cntb       = (int*)(ws + off);          off += align_up((size_t)NBC * 4);
    int*          bptr       = (int*)(ws + off);          off += align_up((size_t)(NBC + 1) * 4);
    int*          cursor     = (int*)(ws + off);          off += align_up((size_t)NBC * 4);
    int2*         rowinfo    = (int2*)(ws + off);         off += align_up((size_t)n_nodes * 8);
    float*        r          = (float*)(ws + off);        off += align_up((size_t)n_nodes * 4);
    float*        rinv       = (float*)(ws + off);        off += align_up((size_t)n_nodes * 4);
    unsigned int* staged     = (unsigned int*)(ws + off); off += align_up((size_t)E * 4);
    int*          sorted_src = (int*)(ws + off);          off += align_up((size_t)E * 4);
    unsigned short* xs0      = (unsigned short*)(ws + off); off += align_up(((size_t)totalK + KD) * 2);
    unsigned short* xs1      = (unsigned short*)(ws + off); off += align_up(((size_t)totalK + KD) * 2);
    unsigned short* xs2      = (unsigned short*)(ws + off); off += align_up(((size_t)totalK + KD) * 2);
    if (off > ws_size) return;

    float* out = (float*)d_out;

    const int BLK = 256;
    const int grid_v = 2048;
    const int grid_g = (n_nodes * KD + BLK - 1) / BLK;  // 1 wave/node
    const int zrow = n_nodes;                            // zeroed sentinel row

    // zero sentinel rows + counters
    hipMemsetAsync(cntb, 0, (size_t)NBC * 4, stream);
    hipMemsetAsync(xs0 + (size_t)n_nodes * KD, 0, KD * 2, stream);
    hipMemsetAsync(xs1 + (size_t)n_nodes * KD, 0, KD * 2, stream);
    hipMemsetAsync(xs2 + (size_t)n_nodes * KD, 0, KD * 2, stream);

    // build: coarse hist -> scan -> tile multisplit -> per-bucket exact sort
    bhist_kernel<<<256, BLK, (size_t)NBC * 4, stream>>>(dst, cntb, E, NBC);
    scan_small_kernel<<<1, 256, 0, stream>>>(cntb, bptr, cursor, NBC, E);
    csplit_kernel<<<ntiles, BLK, 0, stream>>>(src, dst, cursor, staged, E, NBC, ntiles);
    csort_kernel<<<NBC, BLK, 0, stream>>>(staged, bptr, sorted_src, rowinfo, r, rinv,
                                          n_nodes, E);

    // xs0 = fp16(x0 * r)
    combine_kernel<<<grid_v, BLK, 0, stream>>>((const float4*)Gu, (const float4*)Gi,
                                               (const float4*)Gut, (const float4*)Git,
                                               r, (ushort4*)xs0, nu4, total4);

    // propagation: xs1, xs2, then fused last layer -> out
    gather_kernel<<<grid_g, BLK, 0, stream>>>(rowinfo, sorted_src, r,
                                              (const uint2*)xs0, (ushort4*)xs1,
                                              nullptr, nullptr, nullptr, nullptr,
                                              nullptr, nullptr, nullptr, nullptr,
                                              nu, n_nodes, zrow, 0);
    gather_kernel<<<grid_g, BLK, 0, stream>>>(rowinfo, sorted_src, r,
                                              (const uint2*)xs1, (ushort4*)xs2,
                                              nullptr, nullptr, nullptr, nullptr,
                                              nullptr, nullptr, nullptr, nullptr,
                                              nu, n_nodes, zrow, 0);
    gather_kernel<<<grid_g, BLK, 0, stream>>>(rowinfo, sorted_src, r,
                                              (const uint2*)xs2, nullptr,
                                              (const float4*)Gu, (const float4*)Gi,
                                              (const float4*)Gut, (const float4*)Git,
                                              rinv, (const ushort4*)xs1,
                                              (const ushort4*)xs2,
                                              (float4*)out, nu, n_nodes, zrow, 1);
}

// Round 13
// 237.556 us; speedup vs baseline: 1.2509x; 1.1232x over previous
//
#include <hip/hip_runtime.h>
#include <hip/hip_fp16.h>

#define KD 64        // embedding dim
#define NPC 1024     // nodes per coarse bucket (bucket = dst >> 10)
#define TILE 4096    // edges per csplit tile

__device__ __forceinline__ float h2f(unsigned short u) {
    return __half2float(__ushort_as_half(u));
}
__device__ __forceinline__ unsigned short f2h(float f) {
    return __half_as_ushort(__float2half(f));
}

// ---------------- build: coarse histogram ----------------

__global__ void bhist_kernel(const int* __restrict__ dst, int* __restrict__ cntb,
                             int E, int NBC) {
    extern __shared__ int lcnt[];
    for (int i = threadIdx.x; i < NBC; i += blockDim.x) lcnt[i] = 0;
    __syncthreads();
    for (int i = blockIdx.x * blockDim.x + threadIdx.x; i < E; i += gridDim.x * blockDim.x)
        atomicAdd(&lcnt[dst[i] >> 10], 1);
    __syncthreads();
    for (int i = threadIdx.x; i < NBC; i += blockDim.x) {
        int v = lcnt[i];
        if (v) atomicAdd(&cntb[i], v);
    }
}

// single-block exclusive scan of NBC (<=256) counters -> bptr, cursor
__global__ void scan_small_kernel(const int* __restrict__ cnt, int* __restrict__ bptr,
                                  int* __restrict__ cursor, int n, int E) {
    __shared__ int s[256];
    int t = threadIdx.x;
    int v = (t < n) ? cnt[t] : 0;
    s[t] = v;
    __syncthreads();
    for (int off = 1; off < 256; off <<= 1) {
        int add = (t >= off) ? s[t - off] : 0;
        __syncthreads();
        s[t] += add;
        __syncthreads();
    }
    int excl = s[t] - v;
    if (t < n) { bptr[t] = excl; cursor[t] = excl; }
    if (t == 0) bptr[n] = E;
}

// ---------------- build: tile multisplit (pass 1) ----------------

__global__ __launch_bounds__(256)
void csplit_kernel(const int* __restrict__ src, const int* __restrict__ dst,
                   int* __restrict__ cursor, unsigned int* __restrict__ staged,
                   int E, int NBC, int ntiles) {
    __shared__ unsigned int  ord[TILE];      // 16 KB ordered packed entries
    __shared__ unsigned short obkt[TILE];    // 8 KB bucket id per ordered slot
    __shared__ int hist[256];
    __shared__ int lofs[256];
    __shared__ int gbase[256];
    int tid = threadIdx.x;

    for (int tile = blockIdx.x; tile < ntiles; tile += gridDim.x) {
        int e0 = tile * TILE;
        int n = E - e0; if (n > TILE) n = TILE;

        if (tid < NBC) hist[tid] = 0;
        __syncthreads();
        for (int i = tid; i < n; i += 256)
            atomicAdd(&hist[dst[e0 + i] >> 10], 1);
        __syncthreads();
        int v = (tid < NBC) ? hist[tid] : 0;
        lofs[tid] = v;
        __syncthreads();
        for (int off = 1; off < 256; off <<= 1) {
            int add = (tid >= off) ? lofs[tid - off] : 0;
            __syncthreads();
            lofs[tid] += add;
            __syncthreads();
        }
        int excl = lofs[tid] - v;
        lofs[tid] = excl;
        if (tid < NBC) {
            gbase[tid] = atomicAdd(&cursor[tid], v);
            hist[tid] = 0;
        }
        __syncthreads();
        for (int i = tid; i < n; i += 256) {
            int dd = dst[e0 + i];
            int ss = src[e0 + i];
            int b = dd >> 10;
            int p = lofs[b] + atomicAdd(&hist[b], 1);
            ord[p] = (unsigned int)ss | (((unsigned int)dd & 1023u) << 18);
            obkt[p] = (unsigned short)b;
        }
        __syncthreads();
        for (int i = tid; i < n; i += 256) {
            int b = obkt[i];
            staged[gbase[b] + (i - lofs[b])] = ord[i];
        }
        __syncthreads();
    }
}

// ---------------- build: exact per-bucket sort (pass 2) ----------------

__global__ __launch_bounds__(256)
void csort_kernel(const unsigned int* __restrict__ staged, const int* __restrict__ bptr,
                  int* __restrict__ sorted_src, int2* __restrict__ rowinfo,
                  float* __restrict__ r, float* __restrict__ rinv,
                  int n_nodes, int E) {
    __shared__ int cnt[NPC];
    __shared__ int lofs[NPC];
    __shared__ int wsum[256];
    int b = blockIdx.x;
    int tid = threadIdx.x;
    int begin = bptr[b], end = bptr[b + 1];

    for (int i = tid; i < NPC; i += 256) cnt[i] = 0;
    __syncthreads();
    for (int i = begin + tid; i < end; i += 256)
        atomicAdd(&cnt[(staged[i] >> 18) & 1023u], 1);
    __syncthreads();
    int base = tid * 4;
    int c0 = cnt[base], c1 = cnt[base + 1], c2 = cnt[base + 2], c3 = cnt[base + 3];
    int tsum = c0 + c1 + c2 + c3;
    wsum[tid] = tsum;
    __syncthreads();
    for (int off = 1; off < 256; off <<= 1) {
        int add = (tid >= off) ? wsum[tid - off] : 0;
        __syncthreads();
        wsum[tid] += add;
        __syncthreads();
    }
    int texcl = wsum[tid] - tsum;
    lofs[base]     = texcl;
    lofs[base + 1] = texcl + c0;
    lofs[base + 2] = texcl + c0 + c1;
    lofs[base + 3] = texcl + c0 + c1 + c2;
    int node0 = b * NPC + base;
    int cc[4] = {c0, c1, c2, c3};
    for (int j = 0; j < 4; ++j) {
        int node = node0 + j;
        if (node < n_nodes) {
            float d = fmaxf((float)cc[j], 1.0f);
            rowinfo[node] = make_int2(begin + lofs[base + j], cc[j]);
            r[node] = rsqrtf(d);
            rinv[node] = sqrtf(d);
        }
    }
    cnt[base] = 0; cnt[base + 1] = 0; cnt[base + 2] = 0; cnt[base + 3] = 0;
    __syncthreads();
    for (int i = begin + tid; i < end; i += 256) {
        unsigned int u = staged[i];
        int ld = (u >> 18) & 1023u;
        int p = begin + lofs[ld] + atomicAdd(&cnt[ld], 1);
        sorted_src[p] = (int)(u & 0x3FFFFu);
    }
}

// ---------------- embedding kernels ----------------

// xs0 = fp16((Gu+Gut | Gi+Git) * r[node])
__global__ void combine_kernel(const float4* __restrict__ Gu, const float4* __restrict__ Gi,
                               const float4* __restrict__ Gut, const float4* __restrict__ Git,
                               const float* __restrict__ r,
                               ushort4* __restrict__ xs,
                               int nu4, int total4) {
    for (int i = blockIdx.x * blockDim.x + threadIdx.x; i < total4; i += gridDim.x * blockDim.x) {
        float4 a, b;
        if (i < nu4) { a = Gu[i]; b = Gut[i]; }
        else         { a = Gi[i - nu4]; b = Git[i - nu4]; }
        float rr = r[i >> 4];
        ushort4 p;
        p.x = f2h((a.x + b.x) * rr); p.y = f2h((a.y + b.y) * rr);
        p.z = f2h((a.z + b.z) * rr); p.w = f2h((a.w + b.w) * rr);
        xs[i] = p;
    }
}

// TWO nodes per wave (n0 = 2*wid, n1 = 2*wid+1): 4 subgroups x 16 lanes;
// inner iter issues 8 independent 8B fp16 row loads (4 per node) before any
// math -> 2x memory-level parallelism vs 1 node/wave. Invalid slots select a
// zeroed sentinel row. After xor-reduce (16/32) every lane holds both totals;
// lanes 0-15 write n0, lanes 16-31 write n1 (contiguous 32-element window).
// last=0: xs_next = fp16(acc*r*r); last=1: fused epilogue writes final out.
__global__ __launch_bounds__(256)
void gather_kernel(const int2* __restrict__ rowinfo, const int* __restrict__ sorted_src,
                   const float* __restrict__ r, const uint2* __restrict__ xs,
                   ushort4* __restrict__ xs_next,
                   const float4* __restrict__ Gu, const float4* __restrict__ Gi,
                   const float4* __restrict__ Gut, const float4* __restrict__ Git,
                   const float* __restrict__ rinv,
                   const ushort4* __restrict__ xs1, const ushort4* __restrict__ xs2,
                   float4* __restrict__ out, int nu, int N, int zrow, int last) {
    int wid = (blockIdx.x * blockDim.x + threadIdx.x) >> 6;
    int lane = threadIdx.x & 63;
    int n0 = wid * 2;
    int n1 = n0 + 1;
    if (n0 >= N) return;
    int2 ri0 = rowinfo[n0];
    int2 ri1 = (n1 < N) ? rowinfo[n1] : make_int2(0, 0);
    int sub = lane >> 4;      // subgroup 0..3
    int li  = lane & 15;      // 8B slot within the 64-dim fp16 row

    float ax0 = 0.f, ay0 = 0.f, az0 = 0.f, aw0 = 0.f;
    float ax1 = 0.f, ay1 = 0.f, az1 = 0.f, aw1 = 0.f;
    int maxy = ri0.y > ri1.y ? ri0.y : ri1.y;

    for (int boff = 0; boff < maxy; boff += 64) {
        int nb0 = ri0.y - boff; nb0 = nb0 < 0 ? 0 : (nb0 > 64 ? 64 : nb0);
        int nb1 = ri1.y - boff; nb1 = nb1 < 0 ? 0 : (nb1 > 64 ? 64 : nb1);
        int es0 = 0, es1 = 0;
        if (nb0 > 0) {
            int e = ri0.x + boff + lane;
            int laste = ri0.x + ri0.y - 1;
            es0 = sorted_src[e > laste ? laste : e];
        }
        if (nb1 > 0) {
            int e = ri1.x + boff + lane;
            int laste = ri1.x + ri1.y - 1;
            es1 = sorted_src[e > laste ? laste : e];
        }
        int nbm = nb0 > nb1 ? nb0 : nb1;
        for (int c = 0; c < nbm; c += 16) {
            int j0 = c + sub * 4;
            int t0 = __shfl(es0, j0 + 0);
            int t1 = __shfl(es0, j0 + 1);
            int t2 = __shfl(es0, j0 + 2);
            int t3 = __shfl(es0, j0 + 3);
            int q0 = __shfl(es1, j0 + 0);
            int q1 = __shfl(es1, j0 + 1);
            int q2 = __shfl(es1, j0 + 2);
            int q3 = __shfl(es1, j0 + 3);
            t0 = (j0     < nb0) ? t0 : zrow;
            t1 = (j0 + 1 < nb0) ? t1 : zrow;
            t2 = (j0 + 2 < nb0) ? t2 : zrow;
            t3 = (j0 + 3 < nb0) ? t3 : zrow;
            q0 = (j0     < nb1) ? q0 : zrow;
            q1 = (j0 + 1 < nb1) ? q1 : zrow;
            q2 = (j0 + 2 < nb1) ? q2 : zrow;
            q3 = (j0 + 3 < nb1) ? q3 : zrow;
            uint2 w0 = xs[t0 * 16 + li];
            uint2 w1 = xs[t1 * 16 + li];
            uint2 w2 = xs[t2 * 16 + li];
            uint2 w3 = xs[t3 * 16 + li];
            uint2 v0 = xs[q0 * 16 + li];
            uint2 v1 = xs[q1 * 16 + li];
            uint2 v2 = xs[q2 * 16 + li];
            uint2 v3 = xs[q3 * 16 + li];
            {
                __half2 sa = __hadd2(__hadd2(__builtin_bit_cast(__half2, w0.x),
                                             __builtin_bit_cast(__half2, w1.x)),
                                     __hadd2(__builtin_bit_cast(__half2, w2.x),
                                             __builtin_bit_cast(__half2, w3.x)));
                __half2 sb = __hadd2(__hadd2(__builtin_bit_cast(__half2, w0.y),
                                             __builtin_bit_cast(__half2, w1.y)),
                                     __hadd2(__builtin_bit_cast(__half2, w2.y),
                                             __builtin_bit_cast(__half2, w3.y)));
                float2 fa = __half22float2(sa);
                float2 fb = __half22float2(sb);
                ax0 += fa.x; ay0 += fa.y; az0 += fb.x; aw0 += fb.y;
            }
            {
                __half2 sa = __hadd2(__hadd2(__builtin_bit_cast(__half2, v0.x),
                                             __builtin_bit_cast(__half2, v1.x)),
                                     __hadd2(__builtin_bit_cast(__half2, v2.x),
                                             __builtin_bit_cast(__half2, v3.x)));
                __half2 sb = __hadd2(__hadd2(__builtin_bit_cast(__half2, v0.y),
                                             __builtin_bit_cast(__half2, v1.y)),
                                     __hadd2(__builtin_bit_cast(__half2, v2.y),
                                             __builtin_bit_cast(__half2, v3.y)));
                float2 fa = __half22float2(sa);
                float2 fb = __half22float2(sb);
                ax1 += fa.x; ay1 += fa.y; az1 += fb.x; aw1 += fb.y;
            }
        }
    }
    ax0 += __shfl_xor(ax0, 16); ay0 += __shfl_xor(ay0, 16);
    az0 += __shfl_xor(az0, 16); aw0 += __shfl_xor(aw0, 16);
    ax1 += __shfl_xor(ax1, 16); ay1 += __shfl_xor(ay1, 16);
    az1 += __shfl_xor(az1, 16); aw1 += __shfl_xor(aw1, 16);
    ax0 += __shfl_xor(ax0, 32); ay0 += __shfl_xor(ay0, 32);
    az0 += __shfl_xor(az0, 32); aw0 += __shfl_xor(aw0, 32);
    ax1 += __shfl_xor(ax1, 32); ay1 += __shfl_xor(ay1, 32);
    az1 += __shfl_xor(az1, 32); aw1 += __shfl_xor(aw1, 32);

    int node = (lane < 16) ? n0 : n1;
    int lli  = lane & 15;
    if (lane < 32 && node < N) {
        float sx = (lane < 16) ? ax0 : ax1;
        float sy = (lane < 16) ? ay0 : ay1;
        float sz = (lane < 16) ? az0 : az1;
        float sw = (lane < 16) ? aw0 : aw1;
        float rr = r[node];
        int idx = node * 16 + lli;
        if (!last) {
            float s = rr * rr;
            ushort4 p;
            p.x = f2h(sx * s); p.y = f2h(sy * s);
            p.z = f2h(sz * s); p.w = f2h(sw * s);
            xs_next[idx] = p;
        } else {
            const float a1 = 0.5f, a2 = 1.0f / 3.0f, a3 = 0.25f;
            float4 a, b;
            if (node < nu) { a = Gu[idx]; b = Gut[idx]; }
            else           { int j = idx - nu * 16; a = Gi[j]; b = Git[j]; }
            float rv = rinv[node];
            ushort4 u1 = xs1[idx];
            ushort4 u2 = xs2[idx];
            float4 o;
            o.x = a.x + b.x + rv * (a1 * h2f(u1.x) + a2 * h2f(u2.x)) + a3 * (sx * rr);
            o.y = a.y + b.y + rv * (a1 * h2f(u1.y) + a2 * h2f(u2.y)) + a3 * (sy * rr);
            o.z = a.z + b.z + rv * (a1 * h2f(u1.z) + a2 * h2f(u2.z)) + a3 * (sz * rr);
            o.w = a.w + b.w + rv * (a1 * h2f(u1.w) + a2 * h2f(u2.w)) + a3 * (sw * rr);
            out[idx] = o;
        }
    }
}

// ---------------- launch ----------------

extern "C" void kernel_launch(void* const* d_in, const int* in_sizes, int n_in,
                              void* d_out, int out_size, void* d_ws, size_t ws_size,
                              hipStream_t stream) {
    const float* Gu  = (const float*)d_in[0];
    const float* Gi  = (const float*)d_in[1];
    const float* Gut = (const float*)d_in[2];
    const float* Git = (const float*)d_in[3];
    const int*   edge_index = (const int*)d_in[4];

    const int nuK = in_sizes[0];
    const int niK = in_sizes[1];
    const int n_nodes = (nuK + niK) / KD;        // 150000
    const int E = in_sizes[4] / 2;               // 2,000,000
    const int totalK = nuK + niK;
    const int total4 = totalK / 4;
    const int nu4 = nuK / 4;
    const int nu = nuK / KD;                     // 100000
    const int NBC = (n_nodes + NPC - 1) / NPC;   // 147 coarse buckets
    const int ntiles = (E + TILE - 1) / TILE;    // 489

    const int* src = edge_index;
    const int* dst = edge_index + E;

    auto align_up = [](size_t v) { return (v + 255) & ~(size_t)255; };
    char* ws = (char*)d_ws;
    size_t off = 0;
    int*          cntb       = (int*)(ws + off);          off += align_up((size_t)NBC * 4);
    int*          bptr       = (int*)(ws + off);          off += align_up((size_t)(NBC + 1) * 4);
    int*          cursor     = (int*)(ws + off);          off += align_up((size_t)NBC * 4);
    int2*         rowinfo    = (int2*)(ws + off);         off += align_up((size_t)n_nodes * 8);
    float*        r          = (float*)(ws + off);        off += align_up((size_t)n_nodes * 4);
    float*        rinv       = (float*)(ws + off);        off += align_up((size_t)n_nodes * 4);
    unsigned int* staged     = (unsigned int*)(ws + off); off += align_up((size_t)E * 4);
    int*          sorted_src = (int*)(ws + off);          off += align_up((size_t)E * 4);
    unsigned short* xs0      = (unsigned short*)(ws + off); off += align_up(((size_t)totalK + KD) * 2);
    unsigned short* xs1      = (unsigned short*)(ws + off); off += align_up(((size_t)totalK + KD) * 2);
    unsigned short* xs2      = (unsigned short*)(ws + off); off += align_up(((size_t)totalK + KD) * 2);
    if (off > ws_size) return;

    float* out = (float*)d_out;

    const int BLK = 256;
    const int grid_v = 2048;
    const int n_waves = (n_nodes + 1) / 2;               // 2 nodes per wave
    const int grid_g = ((size_t)n_waves * 64 + BLK - 1) / BLK;
    const int zrow = n_nodes;                            // zeroed sentinel row

    // zero sentinel rows + counters
    hipMemsetAsync(cntb, 0, (size_t)NBC * 4, stream);
    hipMemsetAsync(xs0 + (size_t)n_nodes * KD, 0, KD * 2, stream);
    hipMemsetAsync(xs1 + (size_t)n_nodes * KD, 0, KD * 2, stream);
    hipMemsetAsync(xs2 + (size_t)n_nodes * KD, 0, KD * 2, stream);

    // build: coarse hist -> scan -> tile multisplit -> per-bucket exact sort
    bhist_kernel<<<256, BLK, (size_t)NBC * 4, stream>>>(dst, cntb, E, NBC);
    scan_small_kernel<<<1, 256, 0, stream>>>(cntb, bptr, cursor, NBC, E);
    csplit_kernel<<<ntiles, BLK, 0, stream>>>(src, dst, cursor, staged, E, NBC, ntiles);
    csort_kernel<<<NBC, BLK, 0, stream>>>(staged, bptr, sorted_src, rowinfo, r, rinv,
                                          n_nodes, E);

    // xs0 = fp16(x0 * r)
    combine_kernel<<<grid_v, BLK, 0, stream>>>((const float4*)Gu, (const float4*)Gi,
                                               (const float4*)Gut, (const float4*)Git,
                                               r, (ushort4*)xs0, nu4, total4);

    // propagation: xs1, xs2, then fused last layer -> out
    gather_kernel<<<grid_g, BLK, 0, stream>>>(rowinfo, sorted_src, r,
                                              (const uint2*)xs0, (ushort4*)xs1,
                                              nullptr, nullptr, nullptr, nullptr,
                                              nullptr, nullptr, nullptr, nullptr,
                                              nu, n_nodes, zrow, 0);
    gather_kernel<<<grid_g, BLK, 0, stream>>>(rowinfo, sorted_src, r,
                                              (const uint2*)xs1, (ushort4*)xs2,
                                              nullptr, nullptr, nullptr, nullptr,
                                              nullptr, nullptr, nullptr, nullptr,
                                              nu, n_nodes, zrow, 0);
    gather_kernel<<<grid_g, BLK, 0, stream>>>(rowinfo, sorted_src, r,
                                              (const uint2*)xs2, nullptr,
                                              (const float4*)Gu, (const float4*)Gi,
                                              (const float4*)Gut, (const float4*)Git,
                                              rinv, (const ushort4*)xs1,
                                              (const ushort4*)xs2,
                                              (float4*)out, nu, n_nodes, zrow, 1);
}

// Round 14
// 230.641 us; speedup vs baseline: 1.2884x; 1.0300x over previous
//
#include <hip/hip_runtime.h>
#include <hip/hip_fp16.h>

#define KD 64        // embedding dim
#define NPC 1024     // nodes per coarse bucket (bucket = dst >> 10)
#define TILE 2048    // edges per csplit tile

__device__ __forceinline__ float h2f(unsigned short u) {
    return __half2float(__ushort_as_half(u));
}
__device__ __forceinline__ unsigned short f2h(float f) {
    return __half_as_ushort(__float2half(f));
}

// ---------------- build: coarse histogram ----------------

__global__ void bhist_kernel(const int* __restrict__ dst, int* __restrict__ cntb,
                             int E, int NBC) {
    extern __shared__ int lcnt[];
    for (int i = threadIdx.x; i < NBC; i += blockDim.x) lcnt[i] = 0;
    __syncthreads();
    for (int i = blockIdx.x * blockDim.x + threadIdx.x; i < E; i += gridDim.x * blockDim.x)
        atomicAdd(&lcnt[dst[i] >> 10], 1);
    __syncthreads();
    for (int i = threadIdx.x; i < NBC; i += blockDim.x) {
        int v = lcnt[i];
        if (v) atomicAdd(&cntb[i], v);
    }
}

// single-block exclusive scan of NBC (<=256) counters -> bptr, cursor
__global__ void scan_small_kernel(const int* __restrict__ cnt, int* __restrict__ bptr,
                                  int* __restrict__ cursor, int n, int E) {
    __shared__ int s[256];
    int t = threadIdx.x;
    int v = (t < n) ? cnt[t] : 0;
    s[t] = v;
    __syncthreads();
    for (int off = 1; off < 256; off <<= 1) {
        int add = (t >= off) ? s[t - off] : 0;
        __syncthreads();
        s[t] += add;
        __syncthreads();
    }
    int excl = s[t] - v;
    if (t < n) { bptr[t] = excl; cursor[t] = excl; }
    if (t == 0) bptr[n] = E;
}

// ---------------- build: tile multisplit (pass 1) ----------------

__global__ __launch_bounds__(256)
void csplit_kernel(const int* __restrict__ src, const int* __restrict__ dst,
                   int* __restrict__ cursor, unsigned int* __restrict__ staged,
                   int E, int NBC, int ntiles) {
    __shared__ unsigned int  ord[TILE];      // 8 KB ordered packed entries
    __shared__ unsigned short obkt[TILE];    // 4 KB bucket id per ordered slot
    __shared__ int hist[256];
    __shared__ int lofs[256];
    __shared__ int gbase[256];
    int tid = threadIdx.x;

    for (int tile = blockIdx.x; tile < ntiles; tile += gridDim.x) {
        int e0 = tile * TILE;
        int n = E - e0; if (n > TILE) n = TILE;

        if (tid < NBC) hist[tid] = 0;
        __syncthreads();
        for (int i = tid; i < n; i += 256)
            atomicAdd(&hist[dst[e0 + i] >> 10], 1);
        __syncthreads();
        int v = (tid < NBC) ? hist[tid] : 0;
        lofs[tid] = v;
        __syncthreads();
        for (int off = 1; off < 256; off <<= 1) {
            int add = (tid >= off) ? lofs[tid - off] : 0;
            __syncthreads();
            lofs[tid] += add;
            __syncthreads();
        }
        int excl = lofs[tid] - v;
        lofs[tid] = excl;
        if (tid < NBC) {
            gbase[tid] = atomicAdd(&cursor[tid], v);
            hist[tid] = 0;
        }
        __syncthreads();
        for (int i = tid; i < n; i += 256) {
            int dd = dst[e0 + i];
            int ss = src[e0 + i];
            int b = dd >> 10;
            int p = lofs[b] + atomicAdd(&hist[b], 1);
            ord[p] = (unsigned int)ss | (((unsigned int)dd & 1023u) << 18);
            obkt[p] = (unsigned short)b;
        }
        __syncthreads();
        for (int i = tid; i < n; i += 256) {
            int b = obkt[i];
            staged[gbase[b] + (i - lofs[b])] = ord[i];
        }
        __syncthreads();
    }
}

// ---------------- build: exact per-bucket sort (pass 2, 1024 threads) ----------------

__global__ __launch_bounds__(1024)
void csort_kernel(const unsigned int* __restrict__ staged, const int* __restrict__ bptr,
                  int* __restrict__ sorted_src, int2* __restrict__ rowinfo,
                  float* __restrict__ r, float* __restrict__ rinv,
                  int n_nodes, int E) {
    __shared__ int cnt[NPC];
    __shared__ int s[NPC];
    __shared__ int lofs[NPC];
    int b = blockIdx.x;
    int tid = threadIdx.x;
    int begin = bptr[b], end = bptr[b + 1];

    cnt[tid] = 0;
    __syncthreads();
    // pass 1: per-node counts (1024-thread stride)
    for (int i = begin + tid; i < end; i += 1024)
        atomicAdd(&cnt[(staged[i] >> 18) & 1023u], 1);
    __syncthreads();
    // exclusive scan over 1024 bins: thread t = bin t, Hillis-Steele
    int v = cnt[tid];
    s[tid] = v;
    __syncthreads();
    for (int off = 1; off < 1024; off <<= 1) {
        int add = (tid >= off) ? s[tid - off] : 0;
        __syncthreads();
        s[tid] += add;
        __syncthreads();
    }
    int excl = s[tid] - v;
    lofs[tid] = excl;
    int node = b * NPC + tid;
    if (node < n_nodes) {
        float d = fmaxf((float)v, 1.0f);
        rowinfo[node] = make_int2(begin + excl, v);
        r[node] = rsqrtf(d);
        rinv[node] = sqrtf(d);
    }
    cnt[tid] = 0;
    __syncthreads();
    // pass 2: scatter within the bucket window
    for (int i = begin + tid; i < end; i += 1024) {
        unsigned int u = staged[i];
        int ld = (u >> 18) & 1023u;
        int p = begin + lofs[ld] + atomicAdd(&cnt[ld], 1);
        sorted_src[p] = (int)(u & 0x3FFFFu);
    }
}

// ---------------- embedding kernels ----------------

// xs0 = fp16((Gu+Gut | Gi+Git) * r[node])
__global__ void combine_kernel(const float4* __restrict__ Gu, const float4* __restrict__ Gi,
                               const float4* __restrict__ Gut, const float4* __restrict__ Git,
                               const float* __restrict__ r,
                               ushort4* __restrict__ xs,
                               int nu4, int total4) {
    for (int i = blockIdx.x * blockDim.x + threadIdx.x; i < total4; i += gridDim.x * blockDim.x) {
        float4 a, b;
        if (i < nu4) { a = Gu[i]; b = Gut[i]; }
        else         { a = Gi[i - nu4]; b = Git[i - nu4]; }
        float rr = r[i >> 4];
        ushort4 p;
        p.x = f2h((a.x + b.x) * rr); p.y = f2h((a.y + b.y) * rr);
        p.z = f2h((a.z + b.z) * rr); p.w = f2h((a.w + b.w) * rr);
        xs[i] = p;
    }
}

// TWO nodes per wave (n0 = 2*wid, n1 = 2*wid+1): 4 subgroups x 16 lanes;
// inner iter issues 8 independent 8B fp16 row loads (4 per node) before any
// math -> 2x memory-level parallelism vs 1 node/wave. Invalid slots select a
// zeroed sentinel row. After xor-reduce (16/32) every lane holds both totals;
// lanes 0-15 write n0, lanes 16-31 write n1 (contiguous 32-element window).
// last=0: xs_next = fp16(acc*r*r); last=1: fused epilogue writes final out.
__global__ __launch_bounds__(256)
void gather_kernel(const int2* __restrict__ rowinfo, const int* __restrict__ sorted_src,
                   const float* __restrict__ r, const uint2* __restrict__ xs,
                   ushort4* __restrict__ xs_next,
                   const float4* __restrict__ Gu, const float4* __restrict__ Gi,
                   const float4* __restrict__ Gut, const float4* __restrict__ Git,
                   const float* __restrict__ rinv,
                   const ushort4* __restrict__ xs1, const ushort4* __restrict__ xs2,
                   float4* __restrict__ out, int nu, int N, int zrow, int last) {
    int wid = (blockIdx.x * blockDim.x + threadIdx.x) >> 6;
    int lane = threadIdx.x & 63;
    int n0 = wid * 2;
    int n1 = n0 + 1;
    if (n0 >= N) return;
    int2 ri0 = rowinfo[n0];
    int2 ri1 = (n1 < N) ? rowinfo[n1] : make_int2(0, 0);
    int sub = lane >> 4;      // subgroup 0..3
    int li  = lane & 15;      // 8B slot within the 64-dim fp16 row

    float ax0 = 0.f, ay0 = 0.f, az0 = 0.f, aw0 = 0.f;
    float ax1 = 0.f, ay1 = 0.f, az1 = 0.f, aw1 = 0.f;
    int maxy = ri0.y > ri1.y ? ri0.y : ri1.y;

    for (int boff = 0; boff < maxy; boff += 64) {
        int nb0 = ri0.y - boff; nb0 = nb0 < 0 ? 0 : (nb0 > 64 ? 64 : nb0);
        int nb1 = ri1.y - boff; nb1 = nb1 < 0 ? 0 : (nb1 > 64 ? 64 : nb1);
        int es0 = 0, es1 = 0;
        if (nb0 > 0) {
            int e = ri0.x + boff + lane;
            int laste = ri0.x + ri0.y - 1;
            es0 = sorted_src[e > laste ? laste : e];
        }
        if (nb1 > 0) {
            int e = ri1.x + boff + lane;
            int laste = ri1.x + ri1.y - 1;
            es1 = sorted_src[e > laste ? laste : e];
        }
        int nbm = nb0 > nb1 ? nb0 : nb1;
        for (int c = 0; c < nbm; c += 16) {
            int j0 = c + sub * 4;
            int t0 = __shfl(es0, j0 + 0);
            int t1 = __shfl(es0, j0 + 1);
            int t2 = __shfl(es0, j0 + 2);
            int t3 = __shfl(es0, j0 + 3);
            int q0 = __shfl(es1, j0 + 0);
            int q1 = __shfl(es1, j0 + 1);
            int q2 = __shfl(es1, j0 + 2);
            int q3 = __shfl(es1, j0 + 3);
            t0 = (j0     < nb0) ? t0 : zrow;
            t1 = (j0 + 1 < nb0) ? t1 : zrow;
            t2 = (j0 + 2 < nb0) ? t2 : zrow;
            t3 = (j0 + 3 < nb0) ? t3 : zrow;
            q0 = (j0     < nb1) ? q0 : zrow;
            q1 = (j0 + 1 < nb1) ? q1 : zrow;
            q2 = (j0 + 2 < nb1) ? q2 : zrow;
            q3 = (j0 + 3 < nb1) ? q3 : zrow;
            uint2 w0 = xs[t0 * 16 + li];
            uint2 w1 = xs[t1 * 16 + li];
            uint2 w2 = xs[t2 * 16 + li];
            uint2 w3 = xs[t3 * 16 + li];
            uint2 v0 = xs[q0 * 16 + li];
            uint2 v1 = xs[q1 * 16 + li];
            uint2 v2 = xs[q2 * 16 + li];
            uint2 v3 = xs[q3 * 16 + li];
            {
                __half2 sa = __hadd2(__hadd2(__builtin_bit_cast(__half2, w0.x),
                                             __builtin_bit_cast(__half2, w1.x)),
                                     __hadd2(__builtin_bit_cast(__half2, w2.x),
                                             __builtin_bit_cast(__half2, w3.x)));
                __half2 sb = __hadd2(__hadd2(__builtin_bit_cast(__half2, w0.y),
                                             __builtin_bit_cast(__half2, w1.y)),
                                     __hadd2(__builtin_bit_cast(__half2, w2.y),
                                             __builtin_bit_cast(__half2, w3.y)));
                float2 fa = __half22float2(sa);
                float2 fb = __half22float2(sb);
                ax0 += fa.x; ay0 += fa.y; az0 += fb.x; aw0 += fb.y;
            }
            {
                __half2 sa = __hadd2(__hadd2(__builtin_bit_cast(__half2, v0.x),
                                             __builtin_bit_cast(__half2, v1.x)),
                                     __hadd2(__builtin_bit_cast(__half2, v2.x),
                                             __builtin_bit_cast(__half2, v3.x)));
                __half2 sb = __hadd2(__hadd2(__builtin_bit_cast(__half2, v0.y),
                                             __builtin_bit_cast(__half2, v1.y)),
                                     __hadd2(__builtin_bit_cast(__half2, v2.y),
                                             __builtin_bit_cast(__half2, v3.y)));
                float2 fa = __half22float2(sa);
                float2 fb = __half22float2(sb);
                ax1 += fa.x; ay1 += fa.y; az1 += fb.x; aw1 += fb.y;
            }
        }
    }
    ax0 += __shfl_xor(ax0, 16); ay0 += __shfl_xor(ay0, 16);
    az0 += __shfl_xor(az0, 16); aw0 += __shfl_xor(aw0, 16);
    ax1 += __shfl_xor(ax1, 16); ay1 += __shfl_xor(ay1, 16);
    az1 += __shfl_xor(az1, 16); aw1 += __shfl_xor(aw1, 16);
    ax0 += __shfl_xor(ax0, 32); ay0 += __shfl_xor(ay0, 32);
    az0 += __shfl_xor(az0, 32); aw0 += __shfl_xor(aw0, 32);
    ax1 += __shfl_xor(ax1, 32); ay1 += __shfl_xor(ay1, 32);
    az1 += __shfl_xor(az1, 32); aw1 += __shfl_xor(aw1, 32);

    int node = (lane < 16) ? n0 : n1;
    int lli  = lane & 15;
    if (lane < 32 && node < N) {
        float sx = (lane < 16) ? ax0 : ax1;
        float sy = (lane < 16) ? ay0 : ay1;
        float sz = (lane < 16) ? az0 : az1;
        float sw = (lane < 16) ? aw0 : aw1;
        float rr = r[node];
        int idx = node * 16 + lli;
        if (!last) {
            float s = rr * rr;
            ushort4 p;
            p.x = f2h(sx * s); p.y = f2h(sy * s);
            p.z = f2h(sz * s); p.w = f2h(sw * s);
            xs_next[idx] = p;
        } else {
            const float a1 = 0.5f, a2 = 1.0f / 3.0f, a3 = 0.25f;
            float4 a, b;
            if (node < nu) { a = Gu[idx]; b = Gut[idx]; }
            else           { int j = idx - nu * 16; a = Gi[j]; b = Git[j]; }
            float rv = rinv[node];
            ushort4 u1 = xs1[idx];
            ushort4 u2 = xs2[idx];
            float4 o;
            o.x = a.x + b.x + rv * (a1 * h2f(u1.x) + a2 * h2f(u2.x)) + a3 * (sx * rr);
            o.y = a.y + b.y + rv * (a1 * h2f(u1.y) + a2 * h2f(u2.y)) + a3 * (sy * rr);
            o.z = a.z + b.z + rv * (a1 * h2f(u1.z) + a2 * h2f(u2.z)) + a3 * (sz * rr);
            o.w = a.w + b.w + rv * (a1 * h2f(u1.w) + a2 * h2f(u2.w)) + a3 * (sw * rr);
            out[idx] = o;
        }
    }
}

// ---------------- launch ----------------

extern "C" void kernel_launch(void* const* d_in, const int* in_sizes, int n_in,
                              void* d_out, int out_size, void* d_ws, size_t ws_size,
                              hipStream_t stream) {
    const float* Gu  = (const float*)d_in[0];
    const float* Gi  = (const float*)d_in[1];
    const float* Gut = (const float*)d_in[2];
    const float* Git = (const float*)d_in[3];
    const int*   edge_index = (const int*)d_in[4];

    const int nuK = in_sizes[0];
    const int niK = in_sizes[1];
    const int n_nodes = (nuK + niK) / KD;        // 150000
    const int E = in_sizes[4] / 2;               // 2,000,000
    const int totalK = nuK + niK;
    const int total4 = totalK / 4;
    const int nu4 = nuK / 4;
    const int nu = nuK / KD;                     // 100000
    const int NBC = (n_nodes + NPC - 1) / NPC;   // 147 coarse buckets
    const int ntiles = (E + TILE - 1) / TILE;    // 977

    const int* src = edge_index;
    const int* dst = edge_index + E;

    auto align_up = [](size_t v) { return (v + 255) & ~(size_t)255; };
    char* ws = (char*)d_ws;
    size_t off = 0;
    int*          cntb       = (int*)(ws + off);          off += align_up((size_t)NBC * 4);
    int*          bptr       = (int*)(ws + off);          off += align_up((size_t)(NBC + 1) * 4);
    int*          cursor     = (int*)(ws + off);          off += align_up((size_t)NBC * 4);
    int2*         rowinfo    = (int2*)(ws + off);         off += align_up((size_t)n_nodes * 8);
    float*        r          = (float*)(ws + off);        off += align_up((size_t)n_nodes * 4);
    float*        rinv       = (float*)(ws + off);        off += align_up((size_t)n_nodes * 4);
    unsigned int* staged     = (unsigned int*)(ws + off); off += align_up((size_t)E * 4);
    int*          sorted_src = (int*)(ws + off);          off += align_up((size_t)E * 4);
    unsigned short* xs0      = (unsigned short*)(ws + off); off += align_up(((size_t)totalK + KD) * 2);
    unsigned short* xs1      = (unsigned short*)(ws + off); off += align_up(((size_t)totalK + KD) * 2);
    unsigned short* xs2      = (unsigned short*)(ws + off); off += align_up(((size_t)totalK + KD) * 2);
    if (off > ws_size) return;

    float* out = (float*)d_out;

    const int BLK = 256;
    const int grid_v = 2048;
    const int n_waves = (n_nodes + 1) / 2;               // 2 nodes per wave
    const int grid_g = ((size_t)n_waves * 64 + BLK - 1) / BLK;
    const int zrow = n_nodes;                            // zeroed sentinel row

    // zero sentinel rows + counters
    hipMemsetAsync(cntb, 0, (size_t)NBC * 4, stream);
    hipMemsetAsync(xs0 + (size_t)n_nodes * KD, 0, KD * 2, stream);
    hipMemsetAsync(xs1 + (size_t)n_nodes * KD, 0, KD * 2, stream);
    hipMemsetAsync(xs2 + (size_t)n_nodes * KD, 0, KD * 2, stream);

    // build: coarse hist -> scan -> tile multisplit -> per-bucket exact sort
    bhist_kernel<<<256, BLK, (size_t)NBC * 4, stream>>>(dst, cntb, E, NBC);
    scan_small_kernel<<<1, 256, 0, stream>>>(cntb, bptr, cursor, NBC, E);
    csplit_kernel<<<ntiles, BLK, 0, stream>>>(src, dst, cursor, staged, E, NBC, ntiles);
    csort_kernel<<<NBC, 1024, 0, stream>>>(staged, bptr, sorted_src, rowinfo, r, rinv,
                                           n_nodes, E);

    // xs0 = fp16(x0 * r)
    combine_kernel<<<grid_v, BLK, 0, stream>>>((const float4*)Gu, (const float4*)Gi,
                                               (const float4*)Gut, (const float4*)Git,
                                               r, (ushort4*)xs0, nu4, total4);

    // propagation: xs1, xs2, then fused last layer -> out
    gather_kernel<<<grid_g, BLK, 0, stream>>>(rowinfo, sorted_src, r,
                                              (const uint2*)xs0, (ushort4*)xs1,
                                              nullptr, nullptr, nullptr, nullptr,
                                              nullptr, nullptr, nullptr, nullptr,
                                              nu, n_nodes, zrow, 0);
    gather_kernel<<<grid_g, BLK, 0, stream>>>(rowinfo, sorted_src, r,
                                              (const uint2*)xs1, (ushort4*)xs2,
                                              nullptr, nullptr, nullptr, nullptr,
                                              nullptr, nullptr, nullptr, nullptr,
                                              nu, n_nodes, zrow, 0);
    gather_kernel<<<grid_g, BLK, 0, stream>>>(rowinfo, sorted_src, r,
                                              (const uint2*)xs2, nullptr,
                                              (const float4*)Gu, (const float4*)Gi,
                                              (const float4*)Gut, (const float4*)Git,
                                              rinv, (const ushort4*)xs1,
                                              (const ushort4*)xs2,
                                              (float4*)out, nu, n_nodes, zrow, 1);
}

// Round 15
// 224.784 us; speedup vs baseline: 1.3220x; 1.0261x over previous
//
#include <hip/hip_runtime.h>
#include <hip/hip_fp16.h>

#define KD 64        // embedding dim
#define NPC 1024     // nodes per coarse bucket (bucket = dst >> 10)
#define TILE 2048    // edges per csplit tile

__device__ __forceinline__ float h2f(unsigned short u) {
    return __half2float(__ushort_as_half(u));
}
__device__ __forceinline__ unsigned short f2h(float f) {
    return __half_as_ushort(__float2half(f));
}

// ---------------- build: coarse histogram ----------------

__global__ void bhist_kernel(const int* __restrict__ dst, int* __restrict__ cntb,
                             int E, int NBC) {
    extern __shared__ int lcnt[];
    for (int i = threadIdx.x; i < NBC; i += blockDim.x) lcnt[i] = 0;
    __syncthreads();
    for (int i = blockIdx.x * blockDim.x + threadIdx.x; i < E; i += gridDim.x * blockDim.x)
        atomicAdd(&lcnt[dst[i] >> 10], 1);
    __syncthreads();
    for (int i = threadIdx.x; i < NBC; i += blockDim.x) {
        int v = lcnt[i];
        if (v) atomicAdd(&cntb[i], v);
    }
}

// single-block exclusive scan of NBC (<=256) counters -> bptr, cursor
__global__ void scan_small_kernel(const int* __restrict__ cnt, int* __restrict__ bptr,
                                  int* __restrict__ cursor, int n, int E) {
    __shared__ int s[256];
    int t = threadIdx.x;
    int v = (t < n) ? cnt[t] : 0;
    s[t] = v;
    __syncthreads();
    for (int off = 1; off < 256; off <<= 1) {
        int add = (t >= off) ? s[t - off] : 0;
        __syncthreads();
        s[t] += add;
        __syncthreads();
    }
    int excl = s[t] - v;
    if (t < n) { bptr[t] = excl; cursor[t] = excl; }
    if (t == 0) bptr[n] = E;
}

// ---------------- build: tile multisplit (pass 1) ----------------

__global__ __launch_bounds__(256)
void csplit_kernel(const int* __restrict__ src, const int* __restrict__ dst,
                   int* __restrict__ cursor, unsigned int* __restrict__ staged,
                   int E, int NBC, int ntiles) {
    __shared__ unsigned int  ord[TILE];      // 8 KB ordered packed entries
    __shared__ unsigned short obkt[TILE];    // 4 KB bucket id per ordered slot
    __shared__ int hist[256];
    __shared__ int lofs[256];
    __shared__ int gbase[256];
    int tid = threadIdx.x;

    for (int tile = blockIdx.x; tile < ntiles; tile += gridDim.x) {
        int e0 = tile * TILE;
        int n = E - e0; if (n > TILE) n = TILE;

        if (tid < NBC) hist[tid] = 0;
        __syncthreads();
        for (int i = tid; i < n; i += 256)
            atomicAdd(&hist[dst[e0 + i] >> 10], 1);
        __syncthreads();
        int v = (tid < NBC) ? hist[tid] : 0;
        lofs[tid] = v;
        __syncthreads();
        for (int off = 1; off < 256; off <<= 1) {
            int add = (tid >= off) ? lofs[tid - off] : 0;
            __syncthreads();
            lofs[tid] += add;
            __syncthreads();
        }
        int excl = lofs[tid] - v;
        lofs[tid] = excl;
        if (tid < NBC) {
            gbase[tid] = atomicAdd(&cursor[tid], v);
            hist[tid] = 0;
        }
        __syncthreads();
        for (int i = tid; i < n; i += 256) {
            int dd = dst[e0 + i];
            int ss = src[e0 + i];
            int b = dd >> 10;
            int p = lofs[b] + atomicAdd(&hist[b], 1);
            ord[p] = (unsigned int)ss | (((unsigned int)dd & 1023u) << 18);
            obkt[p] = (unsigned short)b;
        }
        __syncthreads();
        for (int i = tid; i < n; i += 256) {
            int b = obkt[i];
            staged[gbase[b] + (i - lofs[b])] = ord[i];
        }
        __syncthreads();
    }
}

// ---------------- build: exact per-bucket sort (pass 2, 1024 threads) ----------------

__global__ __launch_bounds__(1024)
void csort_kernel(const unsigned int* __restrict__ staged, const int* __restrict__ bptr,
                  int* __restrict__ sorted_src, int2* __restrict__ rowinfo,
                  float* __restrict__ r, float* __restrict__ rinv,
                  int n_nodes, int E) {
    __shared__ int cnt[NPC];
    __shared__ int s[NPC];
    __shared__ int lofs[NPC];
    int b = blockIdx.x;
    int tid = threadIdx.x;
    int begin = bptr[b], end = bptr[b + 1];

    cnt[tid] = 0;
    __syncthreads();
    for (int i = begin + tid; i < end; i += 1024)
        atomicAdd(&cnt[(staged[i] >> 18) & 1023u], 1);
    __syncthreads();
    int v = cnt[tid];
    s[tid] = v;
    __syncthreads();
    for (int off = 1; off < 1024; off <<= 1) {
        int add = (tid >= off) ? s[tid - off] : 0;
        __syncthreads();
        s[tid] += add;
        __syncthreads();
    }
    int excl = s[tid] - v;
    lofs[tid] = excl;
    int node = b * NPC + tid;
    if (node < n_nodes) {
        float d = fmaxf((float)v, 1.0f);
        rowinfo[node] = make_int2(begin + excl, v);
        r[node] = rsqrtf(d);
        rinv[node] = sqrtf(d);
    }
    cnt[tid] = 0;
    __syncthreads();
    for (int i = begin + tid; i < end; i += 1024) {
        unsigned int u = staged[i];
        int ld = (u >> 18) & 1023u;
        int p = begin + lofs[ld] + atomicAdd(&cnt[ld], 1);
        sorted_src[p] = (int)(u & 0x3FFFFu);
    }
}

// ---------------- embedding kernels ----------------

// xs0 = fp16((Gu+Gut | Gi+Git) * r[node])
__global__ void combine_kernel(const float4* __restrict__ Gu, const float4* __restrict__ Gi,
                               const float4* __restrict__ Gut, const float4* __restrict__ Git,
                               const float* __restrict__ r,
                               ushort4* __restrict__ xs,
                               int nu4, int total4) {
    for (int i = blockIdx.x * blockDim.x + threadIdx.x; i < total4; i += gridDim.x * blockDim.x) {
        float4 a, b;
        if (i < nu4) { a = Gu[i]; b = Gut[i]; }
        else         { a = Gi[i - nu4]; b = Git[i - nu4]; }
        float rr = r[i >> 4];
        ushort4 p;
        p.x = f2h((a.x + b.x) * rr); p.y = f2h((a.y + b.y) * rr);
        p.z = f2h((a.z + b.z) * rr); p.w = f2h((a.w + b.w) * rr);
        xs[i] = p;
    }
}

// FOUR nodes per wave: subgroup sub (16 lanes) owns node base+sub entirely
// (16 lanes x 8B = full 128B fp16 row). One coalesced 64-lane sorted_src load
// serves 4 nodes (16 edge ids each). Inner: 4x4-edge unroll -> 16 independent
// row loads per lane per chunk. NO cross-lane reduce (acc is lane-local).
// Invalid slots select the zeroed sentinel row. last=0: xs_next=fp16(acc*r*r);
// last=1: fused epilogue writes final out. All 64 lanes write (4 rows, 256B).
__global__ __launch_bounds__(256)
void gather_kernel(const int2* __restrict__ rowinfo, const int* __restrict__ sorted_src,
                   const float* __restrict__ r, const uint2* __restrict__ xs,
                   ushort4* __restrict__ xs_next,
                   const float4* __restrict__ Gu, const float4* __restrict__ Gi,
                   const float4* __restrict__ Gut, const float4* __restrict__ Git,
                   const float* __restrict__ rinv,
                   const ushort4* __restrict__ xs1, const ushort4* __restrict__ xs2,
                   float4* __restrict__ out, int nu, int N, int zrow, int last) {
    int wid = (blockIdx.x * blockDim.x + threadIdx.x) >> 6;
    int lane = threadIdx.x & 63;
    int sub = lane >> 4;          // subgroup = node slot 0..3
    int li  = lane & 15;          // 8B slot within the 64-dim fp16 row
    int node = wid * 4 + sub;
    if (wid * 4 >= N) return;
    int2 ri = (node < N) ? rowinfo[node] : make_int2(0, 0);

    // wave-wide max degree (subgroup-uniform ri.y)
    int maxy = ri.y;
    maxy = max(maxy, __shfl_xor(maxy, 16));
    maxy = max(maxy, __shfl_xor(maxy, 32));

    float ax = 0.f, ay = 0.f, az = 0.f, aw = 0.f;
    int lastp = ri.x + (ri.y > 0 ? ri.y - 1 : 0);

    for (int boff = 0; boff < maxy; boff += 16) {
        // 16 edge ids for this subgroup's node (coalesced across the wave)
        int e = ri.x + boff + li;
        int id = sorted_src[e > lastp ? lastp : e];
        id = (boff + li < ri.y) ? id : zrow;
#pragma unroll
        for (int c = 0; c < 16; c += 4) {
            int sl = (sub << 4) + c;
            int t0 = __shfl(id, sl + 0);
            int t1 = __shfl(id, sl + 1);
            int t2 = __shfl(id, sl + 2);
            int t3 = __shfl(id, sl + 3);
            uint2 w0 = xs[t0 * 16 + li];
            uint2 w1 = xs[t1 * 16 + li];
            uint2 w2 = xs[t2 * 16 + li];
            uint2 w3 = xs[t3 * 16 + li];
            __half2 sa = __hadd2(__hadd2(__builtin_bit_cast(__half2, w0.x),
                                         __builtin_bit_cast(__half2, w1.x)),
                                 __hadd2(__builtin_bit_cast(__half2, w2.x),
                                         __builtin_bit_cast(__half2, w3.x)));
            __half2 sb = __hadd2(__hadd2(__builtin_bit_cast(__half2, w0.y),
                                         __builtin_bit_cast(__half2, w1.y)),
                                 __hadd2(__builtin_bit_cast(__half2, w2.y),
                                         __builtin_bit_cast(__half2, w3.y)));
            float2 fa = __half22float2(sa);
            float2 fb = __half22float2(sb);
            ax += fa.x; ay += fa.y; az += fb.x; aw += fb.y;
        }
    }

    if (node < N) {
        float rr = r[node];
        int idx = node * 16 + li;
        if (!last) {
            float s = rr * rr;
            ushort4 p;
            p.x = f2h(ax * s); p.y = f2h(ay * s);
            p.z = f2h(az * s); p.w = f2h(aw * s);
            xs_next[idx] = p;
        } else {
            const float a1 = 0.5f, a2 = 1.0f / 3.0f, a3 = 0.25f;
            float4 a, b;
            if (node < nu) { a = Gu[idx]; b = Gut[idx]; }
            else           { int j = idx - nu * 16; a = Gi[j]; b = Git[j]; }
            float rv = rinv[node];
            ushort4 u1 = xs1[idx];
            ushort4 u2 = xs2[idx];
            float4 o;
            o.x = a.x + b.x + rv * (a1 * h2f(u1.x) + a2 * h2f(u2.x)) + a3 * (ax * rr);
            o.y = a.y + b.y + rv * (a1 * h2f(u1.y) + a2 * h2f(u2.y)) + a3 * (ay * rr);
            o.z = a.z + b.z + rv * (a1 * h2f(u1.z) + a2 * h2f(u2.z)) + a3 * (az * rr);
            o.w = a.w + b.w + rv * (a1 * h2f(u1.w) + a2 * h2f(u2.w)) + a3 * (aw * rr);
            out[idx] = o;
        }
    }
}

// ---------------- launch ----------------

extern "C" void kernel_launch(void* const* d_in, const int* in_sizes, int n_in,
                              void* d_out, int out_size, void* d_ws, size_t ws_size,
                              hipStream_t stream) {
    const float* Gu  = (const float*)d_in[0];
    const float* Gi  = (const float*)d_in[1];
    const float* Gut = (const float*)d_in[2];
    const float* Git = (const float*)d_in[3];
    const int*   edge_index = (const int*)d_in[4];

    const int nuK = in_sizes[0];
    const int niK = in_sizes[1];
    const int n_nodes = (nuK + niK) / KD;        // 150000
    const int E = in_sizes[4] / 2;               // 2,000,000
    const int totalK = nuK + niK;
    const int total4 = totalK / 4;
    const int nu4 = nuK / 4;
    const int nu = nuK / KD;                     // 100000
    const int NBC = (n_nodes + NPC - 1) / NPC;   // 147 coarse buckets
    const int ntiles = (E + TILE - 1) / TILE;    // 977

    const int* src = edge_index;
    const int* dst = edge_index + E;

    auto align_up = [](size_t v) { return (v + 255) & ~(size_t)255; };
    char* ws = (char*)d_ws;
    size_t off = 0;
    int*          cntb       = (int*)(ws + off);          off += align_up((size_t)NBC * 4);
    int*          bptr       = (int*)(ws + off);          off += align_up((size_t)(NBC + 1) * 4);
    int*          cursor     = (int*)(ws + off);          off += align_up((size_t)NBC * 4);
    int2*         rowinfo    = (int2*)(ws + off);         off += align_up((size_t)n_nodes * 8);
    float*        r          = (float*)(ws + off);        off += align_up((size_t)n_nodes * 4);
    float*        rinv       = (float*)(ws + off);        off += align_up((size_t)n_nodes * 4);
    unsigned int* staged     = (unsigned int*)(ws + off); off += align_up((size_t)E * 4);
    int*          sorted_src = (int*)(ws + off);          off += align_up((size_t)E * 4);
    unsigned short* xs0      = (unsigned short*)(ws + off); off += align_up(((size_t)totalK + KD) * 2);
    unsigned short* xs1      = (unsigned short*)(ws + off); off += align_up(((size_t)totalK + KD) * 2);
    unsigned short* xs2      = (unsigned short*)(ws + off); off += align_up(((size_t)totalK + KD) * 2);
    if (off > ws_size) return;

    float* out = (float*)d_out;

    const int BLK = 256;
    const int grid_v = 2048;
    const int n_waves = (n_nodes + 3) / 4;               // 4 nodes per wave
    const int grid_g = ((size_t)n_waves * 64 + BLK - 1) / BLK;
    const int zrow = n_nodes;                            // zeroed sentinel row

    // zero sentinel rows + counters
    hipMemsetAsync(cntb, 0, (size_t)NBC * 4, stream);
    hipMemsetAsync(xs0 + (size_t)n_nodes * KD, 0, KD * 2, stream);
    hipMemsetAsync(xs1 + (size_t)n_nodes * KD, 0, KD * 2, stream);
    hipMemsetAsync(xs2 + (size_t)n_nodes * KD, 0, KD * 2, stream);

    // build: coarse hist -> scan -> tile multisplit -> per-bucket exact sort
    bhist_kernel<<<256, BLK, (size_t)NBC * 4, stream>>>(dst, cntb, E, NBC);
    scan_small_kernel<<<1, 256, 0, stream>>>(cntb, bptr, cursor, NBC, E);
    csplit_kernel<<<ntiles, BLK, 0, stream>>>(src, dst, cursor, staged, E, NBC, ntiles);
    csort_kernel<<<NBC, 1024, 0, stream>>>(staged, bptr, sorted_src, rowinfo, r, rinv,
                                           n_nodes, E);

    // xs0 = fp16(x0 * r)
    combine_kernel<<<grid_v, BLK, 0, stream>>>((const float4*)Gu, (const float4*)Gi,
                                               (const float4*)Gut, (const float4*)Git,
                                               r, (ushort4*)xs0, nu4, total4);

    // propagation: xs1, xs2, then fused last layer -> out
    gather_kernel<<<grid_g, BLK, 0, stream>>>(rowinfo, sorted_src, r,
                                              (const uint2*)xs0, (ushort4*)xs1,
                                              nullptr, nullptr, nullptr, nullptr,
                                              nullptr, nullptr, nullptr, nullptr,
                                              nu, n_nodes, zrow, 0);
    gather_kernel<<<grid_g, BLK, 0, stream>>>(rowinfo, sorted_src, r,
                                              (const uint2*)xs1, (ushort4*)xs2,
                                              nullptr, nullptr, nullptr, nullptr,
                                              nullptr, nullptr, nullptr, nullptr,
                                              nu, n_nodes, zrow, 0);
    gather_kernel<<<grid_g, BLK, 0, stream>>>(rowinfo, sorted_src, r,
                                              (const uint2*)xs2, nullptr,
                                              (const float4*)Gu, (const float4*)Gi,
                                              (const float4*)Gut, (const float4*)Git,
                                              rinv, (const ushort4*)xs1,
                                              (const ushort4*)xs2,
                                              (float4*)out, nu, n_nodes, zrow, 1);
}

// Round 16
// 206.251 us; speedup vs baseline: 1.4408x; 1.0899x over previous
//
#include <hip/hip_runtime.h>
#include <hip/hip_fp16.h>

#define KD 64        // embedding dim
#define NPC 1024     // nodes per coarse bucket (bucket = dst >> 10)
#define TILE 2048    // edges per csplit tile
#define CAP 16384    // fixed per-bucket capacity (mean 13.6K, +23 sigma)

__device__ __forceinline__ float h2f(unsigned short u) {
    return __half2float(__ushort_as_half(u));
}
__device__ __forceinline__ unsigned short f2h(float f) {
    return __half_as_ushort(__float2half(f));
}

// ---------------- build: cursor init (fixed-capacity buckets) ----------------

__global__ void init_cursor_kernel(int* __restrict__ cursor, int NBC) {
    int i = threadIdx.x;
    if (i < NBC) cursor[i] = i * CAP;
}

// ---------------- build: tile multisplit (pass 1) ----------------

__global__ __launch_bounds__(256)
void csplit_kernel(const int* __restrict__ src, const int* __restrict__ dst,
                   int* __restrict__ cursor, unsigned int* __restrict__ staged,
                   int E, int NBC, int ntiles) {
    __shared__ unsigned int  ord[TILE];      // 8 KB ordered packed entries
    __shared__ unsigned short obkt[TILE];    // 4 KB bucket id per ordered slot
    __shared__ int hist[256];
    __shared__ int lofs[256];
    __shared__ int gbase[256];
    int tid = threadIdx.x;

    for (int tile = blockIdx.x; tile < ntiles; tile += gridDim.x) {
        int e0 = tile * TILE;
        int n = E - e0; if (n > TILE) n = TILE;

        if (tid < NBC) hist[tid] = 0;
        __syncthreads();
        for (int i = tid; i < n; i += 256)
            atomicAdd(&hist[dst[e0 + i] >> 10], 1);
        __syncthreads();
        int v = (tid < NBC) ? hist[tid] : 0;
        lofs[tid] = v;
        __syncthreads();
        for (int off = 1; off < 256; off <<= 1) {
            int add = (tid >= off) ? lofs[tid - off] : 0;
            __syncthreads();
            lofs[tid] += add;
            __syncthreads();
        }
        int excl = lofs[tid] - v;
        lofs[tid] = excl;
        if (tid < NBC) {
            gbase[tid] = atomicAdd(&cursor[tid], v);
            hist[tid] = 0;
        }
        __syncthreads();
        for (int i = tid; i < n; i += 256) {
            int dd = dst[e0 + i];
            int ss = src[e0 + i];
            int b = dd >> 10;
            int p = lofs[b] + atomicAdd(&hist[b], 1);
            ord[p] = (unsigned int)ss | (((unsigned int)dd & 1023u) << 18);
            obkt[p] = (unsigned short)b;
        }
        __syncthreads();
        for (int i = tid; i < n; i += 256) {
            int b = obkt[i];
            staged[gbase[b] + (i - lofs[b])] = ord[i];
        }
        __syncthreads();
    }
}

// ---------------- build: exact per-bucket sort (pass 2, 1024 threads) ----------------

__global__ __launch_bounds__(1024)
void csort_kernel(const unsigned int* __restrict__ staged, const int* __restrict__ cursor,
                  int* __restrict__ sorted_src, int2* __restrict__ rowinfo,
                  float* __restrict__ r, float* __restrict__ rinv,
                  int n_nodes) {
    __shared__ int cnt[NPC];
    __shared__ int s[NPC];
    __shared__ int lofs[NPC];
    int b = blockIdx.x;
    int tid = threadIdx.x;
    int begin = b * CAP;
    int end = cursor[b];

    cnt[tid] = 0;
    __syncthreads();
    for (int i = begin + tid; i < end; i += 1024)
        atomicAdd(&cnt[(staged[i] >> 18) & 1023u], 1);
    __syncthreads();
    int v = cnt[tid];
    s[tid] = v;
    __syncthreads();
    for (int off = 1; off < 1024; off <<= 1) {
        int add = (tid >= off) ? s[tid - off] : 0;
        __syncthreads();
        s[tid] += add;
        __syncthreads();
    }
    int excl = s[tid] - v;
    lofs[tid] = excl;
    int node = b * NPC + tid;
    if (node < n_nodes) {
        float d = fmaxf((float)v, 1.0f);
        rowinfo[node] = make_int2(begin + excl, v);
        r[node] = rsqrtf(d);
        rinv[node] = sqrtf(d);
    }
    cnt[tid] = 0;
    __syncthreads();
    for (int i = begin + tid; i < end; i += 1024) {
        unsigned int u = staged[i];
        int ld = (u >> 18) & 1023u;
        int p = begin + lofs[ld] + atomicAdd(&cnt[ld], 1);
        sorted_src[p] = (int)(u & 0x3FFFFu);
    }
}

// ---------------- embedding kernels ----------------

// xs0 = fp16((Gu+Gut | Gi+Git) * r[node])
__global__ void combine_kernel(const float4* __restrict__ Gu, const float4* __restrict__ Gi,
                               const float4* __restrict__ Gut, const float4* __restrict__ Git,
                               const float* __restrict__ r,
                               ushort4* __restrict__ xs,
                               int nu4, int total4) {
    for (int i = blockIdx.x * blockDim.x + threadIdx.x; i < total4; i += gridDim.x * blockDim.x) {
        float4 a, b;
        if (i < nu4) { a = Gu[i]; b = Gut[i]; }
        else         { a = Gi[i - nu4]; b = Git[i - nu4]; }
        float rr = r[i >> 4];
        ushort4 p;
        p.x = f2h((a.x + b.x) * rr); p.y = f2h((a.y + b.y) * rr);
        p.z = f2h((a.z + b.z) * rr); p.w = f2h((a.w + b.w) * rr);
        xs[i] = p;
    }
}

// FOUR nodes per wave: subgroup sub (16 lanes) owns node base+sub entirely.
// Finished subgroups are exec-masked off (no sentinel load issue). Invalid
// tail slots select the zeroed sentinel row. NO cross-lane reduce.
// last=0: xs_next=fp16(acc*r*r); last=1: fused epilogue writes final out.
__global__ __launch_bounds__(256)
void gather_kernel(const int2* __restrict__ rowinfo, const int* __restrict__ sorted_src,
                   const float* __restrict__ r, const uint2* __restrict__ xs,
                   ushort4* __restrict__ xs_next,
                   const float4* __restrict__ Gu, const float4* __restrict__ Gi,
                   const float4* __restrict__ Gut, const float4* __restrict__ Git,
                   const float* __restrict__ rinv,
                   const ushort4* __restrict__ xs1, const ushort4* __restrict__ xs2,
                   float4* __restrict__ out, int nu, int N, int zrow, int last) {
    int wid = (blockIdx.x * blockDim.x + threadIdx.x) >> 6;
    int lane = threadIdx.x & 63;
    int sub = lane >> 4;          // subgroup = node slot 0..3
    int li  = lane & 15;          // 8B slot within the 64-dim fp16 row
    int node = wid * 4 + sub;
    if (wid * 4 >= N) return;
    int2 ri = (node < N) ? rowinfo[node] : make_int2(0, 0);

    // wave-wide max degree (subgroup-uniform ri.y)
    int maxy = ri.y;
    maxy = max(maxy, __shfl_xor(maxy, 16));
    maxy = max(maxy, __shfl_xor(maxy, 32));

    float ax = 0.f, ay = 0.f, az = 0.f, aw = 0.f;
    int lastp = ri.x + (ri.y > 0 ? ri.y - 1 : 0);

    for (int boff = 0; boff < maxy; boff += 16) {
        int id = zrow;
        bool active = (boff < ri.y);          // subgroup-uniform
        if (active) {
            int e = ri.x + boff + li;
            id = sorted_src[e > lastp ? lastp : e];
            id = (boff + li < ri.y) ? id : zrow;
        }
        if (active) {
#pragma unroll
            for (int c = 0; c < 16; c += 4) {
                int sl = (sub << 4) + c;
                int t0 = __shfl(id, sl + 0);
                int t1 = __shfl(id, sl + 1);
                int t2 = __shfl(id, sl + 2);
                int t3 = __shfl(id, sl + 3);
                uint2 w0 = xs[t0 * 16 + li];
                uint2 w1 = xs[t1 * 16 + li];
                uint2 w2 = xs[t2 * 16 + li];
                uint2 w3 = xs[t3 * 16 + li];
                __half2 sa = __hadd2(__hadd2(__builtin_bit_cast(__half2, w0.x),
                                             __builtin_bit_cast(__half2, w1.x)),
                                     __hadd2(__builtin_bit_cast(__half2, w2.x),
                                             __builtin_bit_cast(__half2, w3.x)));
                __half2 sb = __hadd2(__hadd2(__builtin_bit_cast(__half2, w0.y),
                                             __builtin_bit_cast(__half2, w1.y)),
                                     __hadd2(__builtin_bit_cast(__half2, w2.y),
                                             __builtin_bit_cast(__half2, w3.y)));
                float2 fa = __half22float2(sa);
                float2 fb = __half22float2(sb);
                ax += fa.x; ay += fa.y; az += fb.x; aw += fb.y;
            }
        }
    }

    if (node < N) {
        float rr = r[node];
        int idx = node * 16 + li;
        if (!last) {
            float s = rr * rr;
            ushort4 p;
            p.x = f2h(ax * s); p.y = f2h(ay * s);
            p.z = f2h(az * s); p.w = f2h(aw * s);
            xs_next[idx] = p;
        } else {
            const float a1 = 0.5f, a2 = 1.0f / 3.0f, a3 = 0.25f;
            float4 a, b;
            if (node < nu) { a = Gu[idx]; b = Gut[idx]; }
            else           { int j = idx - nu * 16; a = Gi[j]; b = Git[j]; }
            float rv = rinv[node];
            ushort4 u1 = xs1[idx];
            ushort4 u2 = xs2[idx];
            float4 o;
            o.x = a.x + b.x + rv * (a1 * h2f(u1.x) + a2 * h2f(u2.x)) + a3 * (ax * rr);
            o.y = a.y + b.y + rv * (a1 * h2f(u1.y) + a2 * h2f(u2.y)) + a3 * (ay * rr);
            o.z = a.z + b.z + rv * (a1 * h2f(u1.z) + a2 * h2f(u2.z)) + a3 * (az * rr);
            o.w = a.w + b.w + rv * (a1 * h2f(u1.w) + a2 * h2f(u2.w)) + a3 * (aw * rr);
            out[idx] = o;
        }
    }
}

// ---------------- launch ----------------

extern "C" void kernel_launch(void* const* d_in, const int* in_sizes, int n_in,
                              void* d_out, int out_size, void* d_ws, size_t ws_size,
                              hipStream_t stream) {
    const float* Gu  = (const float*)d_in[0];
    const float* Gi  = (const float*)d_in[1];
    const float* Gut = (const float*)d_in[2];
    const float* Git = (const float*)d_in[3];
    const int*   edge_index = (const int*)d_in[4];

    const int nuK = in_sizes[0];
    const int niK = in_sizes[1];
    const int n_nodes = (nuK + niK) / KD;        // 150000
    const int E = in_sizes[4] / 2;               // 2,000,000
    const int totalK = nuK + niK;
    const int total4 = totalK / 4;
    const int nu4 = nuK / 4;
    const int nu = nuK / KD;                     // 100000
    const int NBC = (n_nodes + NPC - 1) / NPC;   // 147 coarse buckets
    const int ntiles = (E + TILE - 1) / TILE;    // 977

    const int* src = edge_index;
    const int* dst = edge_index + E;

    auto align_up = [](size_t v) { return (v + 255) & ~(size_t)255; };
    char* ws = (char*)d_ws;
    size_t off = 0;
    int*          cursor     = (int*)(ws + off);          off += align_up((size_t)NBC * 4);
    int2*         rowinfo    = (int2*)(ws + off);         off += align_up((size_t)n_nodes * 8);
    float*        r          = (float*)(ws + off);        off += align_up((size_t)n_nodes * 4);
    float*        rinv       = (float*)(ws + off);        off += align_up((size_t)n_nodes * 4);
    unsigned int* staged     = (unsigned int*)(ws + off); off += align_up((size_t)NBC * CAP * 4);
    int*          sorted_src = (int*)(ws + off);          off += align_up((size_t)NBC * CAP * 4);
    unsigned short* xs0      = (unsigned short*)(ws + off); off += align_up(((size_t)totalK + KD) * 2);
    unsigned short* xs1      = (unsigned short*)(ws + off); off += align_up(((size_t)totalK + KD) * 2);
    unsigned short* xs2      = (unsigned short*)(ws + off); off += align_up(((size_t)totalK + KD) * 2);
    if (off > ws_size) return;

    float* out = (float*)d_out;

    const int BLK = 256;
    const int grid_v = 2048;
    const int n_waves = (n_nodes + 3) / 4;               // 4 nodes per wave
    const int grid_g = ((size_t)n_waves * 64 + BLK - 1) / BLK;
    const int zrow = n_nodes;                            // zeroed sentinel row

    // zero sentinel rows; init per-bucket cursors
    hipMemsetAsync(xs0 + (size_t)n_nodes * KD, 0, KD * 2, stream);
    hipMemsetAsync(xs1 + (size_t)n_nodes * KD, 0, KD * 2, stream);
    hipMemsetAsync(xs2 + (size_t)n_nodes * KD, 0, KD * 2, stream);
    init_cursor_kernel<<<1, 256, 0, stream>>>(cursor, NBC);

    // build: tile multisplit into fixed-capacity buckets -> per-bucket exact sort
    csplit_kernel<<<ntiles, BLK, 0, stream>>>(src, dst, cursor, staged, E, NBC, ntiles);
    csort_kernel<<<NBC, 1024, 0, stream>>>(staged, cursor, sorted_src, rowinfo, r, rinv,
                                           n_nodes);

    // xs0 = fp16(x0 * r)
    combine_kernel<<<grid_v, BLK, 0, stream>>>((const float4*)Gu, (const float4*)Gi,
                                               (const float4*)Gut, (const float4*)Git,
                                               r, (ushort4*)xs0, nu4, total4);

    // propagation: xs1, xs2, then fused last layer -> out
    gather_kernel<<<grid_g, BLK, 0, stream>>>(rowinfo, sorted_src, r,
                                              (const uint2*)xs0, (ushort4*)xs1,
                                              nullptr, nullptr, nullptr, nullptr,
                                              nullptr, nullptr, nullptr, nullptr,
                                              nu, n_nodes, zrow, 0);
    gather_kernel<<<grid_g, BLK, 0, stream>>>(rowinfo, sorted_src, r,
                                              (const uint2*)xs1, (ushort4*)xs2,
                                              nullptr, nullptr, nullptr, nullptr,
                                              nullptr, nullptr, nullptr, nullptr,
                                              nu, n_nodes, zrow, 0);
    gather_kernel<<<grid_g, BLK, 0, stream>>>(rowinfo, sorted_src, r,
                                              (const uint2*)xs2, nullptr,
                                              (const float4*)Gu, (const float4*)Gi,
                                              (const float4*)Gut, (const float4*)Git,
                                              rinv, (const ushort4*)xs1,
                                              (const ushort4*)xs2,
                                              (float4*)out, nu, n_nodes, zrow, 1);
}

// Round 17
// 200.489 us; speedup vs baseline: 1.4822x; 1.0287x over previous
//
#include <hip/hip_runtime.h>
#include <hip/hip_fp16.h>

#define KD 64        // embedding dim
#define NPC 1024     // nodes per coarse bucket (bucket = dst >> 10)
#define TILE 2048    // edges per csplit tile
#define CAP 16384    // fixed per-bucket capacity (mean 13.6K, +23 sigma)

__device__ __forceinline__ float h2f(unsigned short u) {
    return __half2float(__ushort_as_half(u));
}
__device__ __forceinline__ unsigned short f2h(float f) {
    return __half_as_ushort(__float2half(f));
}

// ---------------- init: cursors + sentinel rows ----------------

__global__ void init_kernel(int* __restrict__ cursor, int NBC,
                            unsigned short* __restrict__ z0,
                            unsigned short* __restrict__ z1,
                            unsigned short* __restrict__ z2) {
    int i = threadIdx.x;
    if (i < NBC) cursor[i] = i * CAP;
    if (i < KD) { z0[i] = 0; z1[i] = 0; z2[i] = 0; }
}

// ---------------- build: tile multisplit (pass 1) ----------------

// Per 2048-edge tile: LDS hist over NBC buckets (dst cached in LDS), wave-level
// shfl scan (2 barriers vs 16), LDS-ordered scatter, per-bucket reservation,
// rank-ordered coalesced flush into fixed-capacity bucket windows.
__global__ __launch_bounds__(256)
void csplit_kernel(const int* __restrict__ src, const int* __restrict__ dst,
                   int* __restrict__ cursor, unsigned int* __restrict__ staged,
                   int E, int NBC, int ntiles) {
    __shared__ unsigned int  ord[TILE];      // 8 KB ordered packed entries
    __shared__ unsigned short obkt[TILE];    // 4 KB bucket id per ordered slot
    __shared__ int dcache[TILE];             // 8 KB cached dst values
    __shared__ int hist[256];
    __shared__ int lofs[256];
    __shared__ int gbase[256];
    __shared__ int wtot[4];
    int tid = threadIdx.x;
    int wv  = tid >> 6;
    int wl  = tid & 63;

    for (int tile = blockIdx.x; tile < ntiles; tile += gridDim.x) {
        int e0 = tile * TILE;
        int n = E - e0; if (n > TILE) n = TILE;

        if (tid < NBC) hist[tid] = 0;
        __syncthreads();
        // pass A: tile histogram (cache dst)
        for (int i = tid; i < n; i += 256) {
            int dd = dst[e0 + i];
            dcache[i] = dd;
            atomicAdd(&hist[dd >> 10], 1);
        }
        __syncthreads();
        // wave-level inclusive scan of 256 counters (2 barriers)
        int v = (tid < NBC) ? hist[tid] : 0;
        int s = v;
        for (int off = 1; off < 64; off <<= 1) {
            int u = __shfl_up(s, off);
            if (wl >= off) s += u;
        }
        if (wl == 63) wtot[wv] = s;
        __syncthreads();
        int prefix = 0;
        for (int w = 0; w < wv; ++w) prefix += wtot[w];
        int excl = s + prefix - v;
        lofs[tid] = excl;
        // reserve global space; reset hist as local cursor
        if (tid < NBC) {
            gbase[tid] = atomicAdd(&cursor[tid], v);
            hist[tid] = 0;
        }
        __syncthreads();
        // pass B: scatter into LDS-ordered buffer (dst from cache)
        for (int i = tid; i < n; i += 256) {
            int dd = dcache[i];
            int ss = src[e0 + i];
            int b = dd >> 10;
            int p = lofs[b] + atomicAdd(&hist[b], 1);
            ord[p] = (unsigned int)ss | (((unsigned int)dd & 1023u) << 18);
            obkt[p] = (unsigned short)b;
        }
        __syncthreads();
        // pass C: rank-ordered coalesced flush
        for (int i = tid; i < n; i += 256) {
            int b = obkt[i];
            staged[gbase[b] + (i - lofs[b])] = ord[i];
        }
        __syncthreads();
    }
}

// ---------------- build: exact per-bucket sort (pass 2, 1024 threads) ----------------

__global__ __launch_bounds__(1024)
void csort_kernel(const unsigned int* __restrict__ staged, const int* __restrict__ cursor,
                  int* __restrict__ sorted_src, int2* __restrict__ rowinfo,
                  float* __restrict__ r, float* __restrict__ rinv,
                  int n_nodes) {
    __shared__ int cnt[NPC];
    __shared__ int s[NPC];
    __shared__ int lofs[NPC];
    int b = blockIdx.x;
    int tid = threadIdx.x;
    int begin = b * CAP;
    int end = cursor[b];

    cnt[tid] = 0;
    __syncthreads();
    for (int i = begin + tid; i < end; i += 1024)
        atomicAdd(&cnt[(staged[i] >> 18) & 1023u], 1);
    __syncthreads();
    int v = cnt[tid];
    s[tid] = v;
    __syncthreads();
    for (int off = 1; off < 1024; off <<= 1) {
        int add = (tid >= off) ? s[tid - off] : 0;
        __syncthreads();
        s[tid] += add;
        __syncthreads();
    }
    int excl = s[tid] - v;
    lofs[tid] = excl;
    int node = b * NPC + tid;
    if (node < n_nodes) {
        float d = fmaxf((float)v, 1.0f);
        rowinfo[node] = make_int2(begin + excl, v);
        r[node] = rsqrtf(d);
        rinv[node] = sqrtf(d);
    }
    cnt[tid] = 0;
    __syncthreads();
    for (int i = begin + tid; i < end; i += 1024) {
        unsigned int u = staged[i];
        int ld = (u >> 18) & 1023u;
        int p = begin + lofs[ld] + atomicAdd(&cnt[ld], 1);
        sorted_src[p] = (int)(u & 0x3FFFFu);
    }
}

// ---------------- embedding kernels ----------------

// xs0 = fp16((Gu+Gut | Gi+Git) * r[node])
__global__ void combine_kernel(const float4* __restrict__ Gu, const float4* __restrict__ Gi,
                               const float4* __restrict__ Gut, const float4* __restrict__ Git,
                               const float* __restrict__ r,
                               ushort4* __restrict__ xs,
                               int nu4, int total4) {
    for (int i = blockIdx.x * blockDim.x + threadIdx.x; i < total4; i += gridDim.x * blockDim.x) {
        float4 a, b;
        if (i < nu4) { a = Gu[i]; b = Gut[i]; }
        else         { a = Gi[i - nu4]; b = Git[i - nu4]; }
        float rr = r[i >> 4];
        ushort4 p;
        p.x = f2h((a.x + b.x) * rr); p.y = f2h((a.y + b.y) * rr);
        p.z = f2h((a.z + b.z) * rr); p.w = f2h((a.w + b.w) * rr);
        xs[i] = p;
    }
}

// FOUR nodes per wave: subgroup sub (16 lanes) owns node base+sub entirely.
// Finished subgroups are exec-masked off. Invalid tail slots select the zeroed
// sentinel row. NO cross-lane reduce. last=0: xs_next=fp16(acc*r*r);
// last=1: fused epilogue writes final out.
__global__ __launch_bounds__(256)
void gather_kernel(const int2* __restrict__ rowinfo, const int* __restrict__ sorted_src,
                   const float* __restrict__ r, const uint2* __restrict__ xs,
                   ushort4* __restrict__ xs_next,
                   const float4* __restrict__ Gu, const float4* __restrict__ Gi,
                   const float4* __restrict__ Gut, const float4* __restrict__ Git,
                   const float* __restrict__ rinv,
                   const ushort4* __restrict__ xs1, const ushort4* __restrict__ xs2,
                   float4* __restrict__ out, int nu, int N, int zrow, int last) {
    int wid = (blockIdx.x * blockDim.x + threadIdx.x) >> 6;
    int lane = threadIdx.x & 63;
    int sub = lane >> 4;          // subgroup = node slot 0..3
    int li  = lane & 15;          // 8B slot within the 64-dim fp16 row
    int node = wid * 4 + sub;
    if (wid * 4 >= N) return;
    int2 ri = (node < N) ? rowinfo[node] : make_int2(0, 0);

    int maxy = ri.y;
    maxy = max(maxy, __shfl_xor(maxy, 16));
    maxy = max(maxy, __shfl_xor(maxy, 32));

    float ax = 0.f, ay = 0.f, az = 0.f, aw = 0.f;
    int lastp = ri.x + (ri.y > 0 ? ri.y - 1 : 0);

    for (int boff = 0; boff < maxy; boff += 16) {
        int id = zrow;
        bool active = (boff < ri.y);          // subgroup-uniform
        if (active) {
            int e = ri.x + boff + li;
            id = sorted_src[e > lastp ? lastp : e];
            id = (boff + li < ri.y) ? id : zrow;
        }
        if (active) {
#pragma unroll
            for (int c = 0; c < 16; c += 4) {
                int sl = (sub << 4) + c;
                int t0 = __shfl(id, sl + 0);
                int t1 = __shfl(id, sl + 1);
                int t2 = __shfl(id, sl + 2);
                int t3 = __shfl(id, sl + 3);
                uint2 w0 = xs[t0 * 16 + li];
                uint2 w1 = xs[t1 * 16 + li];
                uint2 w2 = xs[t2 * 16 + li];
                uint2 w3 = xs[t3 * 16 + li];
                __half2 sa = __hadd2(__hadd2(__builtin_bit_cast(__half2, w0.x),
                                             __builtin_bit_cast(__half2, w1.x)),
                                     __hadd2(__builtin_bit_cast(__half2, w2.x),
                                             __builtin_bit_cast(__half2, w3.x)));
                __half2 sb = __hadd2(__hadd2(__builtin_bit_cast(__half2, w0.y),
                                             __builtin_bit_cast(__half2, w1.y)),
                                     __hadd2(__builtin_bit_cast(__half2, w2.y),
                                             __builtin_bit_cast(__half2, w3.y)));
                float2 fa = __half22float2(sa);
                float2 fb = __half22float2(sb);
                ax += fa.x; ay += fa.y; az += fb.x; aw += fb.y;
            }
        }
    }

    if (node < N) {
        float rr = r[node];
        int idx = node * 16 + li;
        if (!last) {
            float s = rr * rr;
            ushort4 p;
            p.x = f2h(ax * s); p.y = f2h(ay * s);
            p.z = f2h(az * s); p.w = f2h(aw * s);
            xs_next[idx] = p;
        } else {
            const float a1 = 0.5f, a2 = 1.0f / 3.0f, a3 = 0.25f;
            float4 a, b;
            if (node < nu) { a = Gu[idx]; b = Gut[idx]; }
            else           { int j = idx - nu * 16; a = Gi[j]; b = Git[j]; }
            float rv = rinv[node];
            ushort4 u1 = xs1[idx];
            ushort4 u2 = xs2[idx];
            float4 o;
            o.x = a.x + b.x + rv * (a1 * h2f(u1.x) + a2 * h2f(u2.x)) + a3 * (ax * rr);
            o.y = a.y + b.y + rv * (a1 * h2f(u1.y) + a2 * h2f(u2.y)) + a3 * (ay * rr);
            o.z = a.z + b.z + rv * (a1 * h2f(u1.z) + a2 * h2f(u2.z)) + a3 * (az * rr);
            o.w = a.w + b.w + rv * (a1 * h2f(u1.w) + a2 * h2f(u2.w)) + a3 * (aw * rr);
            out[idx] = o;
        }
    }
}

// ---------------- launch ----------------

extern "C" void kernel_launch(void* const* d_in, const int* in_sizes, int n_in,
                              void* d_out, int out_size, void* d_ws, size_t ws_size,
                              hipStream_t stream) {
    const float* Gu  = (const float*)d_in[0];
    const float* Gi  = (const float*)d_in[1];
    const float* Gut = (const float*)d_in[2];
    const float* Git = (const float*)d_in[3];
    const int*   edge_index = (const int*)d_in[4];

    const int nuK = in_sizes[0];
    const int niK = in_sizes[1];
    const int n_nodes = (nuK + niK) / KD;        // 150000
    const int E = in_sizes[4] / 2;               // 2,000,000
    const int totalK = nuK + niK;
    const int total4 = totalK / 4;
    const int nu4 = nuK / 4;
    const int nu = nuK / KD;                     // 100000
    const int NBC = (n_nodes + NPC - 1) / NPC;   // 147 coarse buckets
    const int ntiles = (E + TILE - 1) / TILE;    // 977

    const int* src = edge_index;
    const int* dst = edge_index + E;

    auto align_up = [](size_t v) { return (v + 255) & ~(size_t)255; };
    char* ws = (char*)d_ws;
    size_t off = 0;
    int*          cursor     = (int*)(ws + off);          off += align_up((size_t)NBC * 4);
    int2*         rowinfo    = (int2*)(ws + off);         off += align_up((size_t)n_nodes * 8);
    float*        r          = (float*)(ws + off);        off += align_up((size_t)n_nodes * 4);
    float*        rinv       = (float*)(ws + off);        off += align_up((size_t)n_nodes * 4);
    unsigned int* staged     = (unsigned int*)(ws + off); off += align_up((size_t)NBC * CAP * 4);
    int*          sorted_src = (int*)(ws + off);          off += align_up((size_t)NBC * CAP * 4);
    unsigned short* xs0      = (unsigned short*)(ws + off); off += align_up(((size_t)totalK + KD) * 2);
    unsigned short* xs1      = (unsigned short*)(ws + off); off += align_up(((size_t)totalK + KD) * 2);
    unsigned short* xs2      = (unsigned short*)(ws + off); off += align_up(((size_t)totalK + KD) * 2);
    if (off > ws_size) return;

    float* out = (float*)d_out;

    const int BLK = 256;
    const int grid_v = 2048;
    const int n_waves = (n_nodes + 3) / 4;               // 4 nodes per wave
    const int grid_g = ((size_t)n_waves * 64 + BLK - 1) / BLK;
    const int zrow = n_nodes;                            // zeroed sentinel row

    // init cursors + zero all three sentinel rows (one kernel)
    init_kernel<<<1, 256, 0, stream>>>(cursor, NBC,
                                       xs0 + (size_t)n_nodes * KD,
                                       xs1 + (size_t)n_nodes * KD,
                                       xs2 + (size_t)n_nodes * KD);

    // build: tile multisplit into fixed-capacity buckets -> per-bucket exact sort
    csplit_kernel<<<ntiles, BLK, 0, stream>>>(src, dst, cursor, staged, E, NBC, ntiles);
    csort_kernel<<<NBC, 1024, 0, stream>>>(staged, cursor, sorted_src, rowinfo, r, rinv,
                                           n_nodes);

    // xs0 = fp16(x0 * r)
    combine_kernel<<<grid_v, BLK, 0, stream>>>((const float4*)Gu, (const float4*)Gi,
                                               (const float4*)Gut, (const float4*)Git,
                                               r, (ushort4*)xs0, nu4, total4);

    // propagation: xs1, xs2, then fused last layer -> out
    gather_kernel<<<grid_g, BLK, 0, stream>>>(rowinfo, sorted_src, r,
                                              (const uint2*)xs0, (ushort4*)xs1,
                                              nullptr, nullptr, nullptr, nullptr,
                                              nullptr, nullptr, nullptr, nullptr,
                                              nu, n_nodes, zrow, 0);
    gather_kernel<<<grid_g, BLK, 0, stream>>>(rowinfo, sorted_src, r,
                                              (const uint2*)xs1, (ushort4*)xs2,
                                              nullptr, nullptr, nullptr, nullptr,
                                              nullptr, nullptr, nullptr, nullptr,
                                              nu, n_nodes, zrow, 0);
    gather_kernel<<<grid_g, BLK, 0, stream>>>(rowinfo, sorted_src, r,
                                              (const uint2*)xs2, nullptr,
                                              (const float4*)Gu, (const float4*)Gi,
                                              (const float4*)Gut, (const float4*)Git,
                                              rinv, (const ushort4*)xs1,
                                              (const ushort4*)xs2,
                                              (float4*)out, nu, n_nodes, zrow, 1);
}